// Round 4
// baseline (1468.920 us; speedup 1.0000x reference)
//
#include <hip/hip_runtime.h>
#include <stdint.h>

#define N_NODES 50000
#define DIN     512
#define DOUT    128
#define NSUP    2
#define EDGES   800000
#define NEDGE   (NSUP * EDGES)        // 1,600,000
#define NROWS   (NSUP * N_NODES)      // 100,000
#define NB      782                   // ceil(NROWS/128)
#define CH      8192                  // edges per bin_scatter block
#define NCH     ((NEDGE + CH - 1) / CH)   // 196
#define EPT     16                    // CH / 512 threads

typedef __attribute__((ext_vector_type(8))) short short8;
typedef __attribute__((ext_vector_type(4))) float f32x4;

// ---- JAX threefry2x32, key(42) -> (0,42); partitionable, bits = o0^o1 (verified R1) ----
__device__ __forceinline__ uint32_t rotl32(uint32_t v, uint32_t d) {
  return (v << d) | (v >> (32u - d));
}

__device__ __forceinline__ void threefry2x32(uint32_t x0, uint32_t x1,
                                             uint32_t& o0, uint32_t& o1) {
  const uint32_t ks0 = 0u;
  const uint32_t ks1 = 42u;
  const uint32_t ks2 = 0u ^ 42u ^ 0x1BD11BDAu;
  x0 += ks0; x1 += ks1;
#define TF_R(r) { x0 += x1; x1 = rotl32(x1, (r)); x1 ^= x0; }
  TF_R(13) TF_R(15) TF_R(26) TF_R(6)
  x0 += ks1; x1 += ks2 + 1u;
  TF_R(17) TF_R(29) TF_R(16) TF_R(24)
  x0 += ks2; x1 += ks0 + 2u;
  TF_R(13) TF_R(15) TF_R(26) TF_R(6)
  x0 += ks0; x1 += ks1 + 3u;
  TF_R(17) TF_R(29) TF_R(16) TF_R(24)
  x0 += ks1; x1 += ks2 + 4u;
  TF_R(13) TF_R(15) TF_R(26) TF_R(6)
  x0 += ks2; x1 += ks0 + 5u;
#undef TF_R
  o0 = x0; o1 = x1;
}

__device__ __forceinline__ bool keep_mask(uint32_t idx) {
  uint32_t o0, o1;
  threefry2x32(0u, idx, o0, o1);
  uint32_t bits = o0 ^ o1;
  float u = __uint_as_float((bits >> 9) | 0x3F800000u) - 1.0f;
  return u < 0.5f;
}

__device__ __forceinline__ uint32_t pack_bf16x2(float a, float b) {
  uint32_t ua = __float_as_uint(a), ub = __float_as_uint(b);
  ua += 0x7fffu + ((ua >> 16) & 1u);
  ub += 0x7fffu + ((ub >> 16) & 1u);
  return (ua >> 16) | (ub & 0xffff0000u);
}

__device__ __forceinline__ uint32_t bf16rne(float f) {
  uint32_t u = __float_as_uint(f);
  u += 0x7fffu + ((u >> 16) & 1u);
  return u >> 16;
}

// ---- W [2][512][128] fp32 -> B16t [256 cols][512 k] bf16 (col = s*128+o) ----
__global__ __launch_bounds__(256) void wcvt(const float* __restrict__ w,
                                            unsigned short* __restrict__ b16t) {
  int i = blockIdx.x * 256 + threadIdx.x;
  if (i >= NSUP * DIN * DOUT) return;
  int s   = i >> 16;
  int rem = i & 65535;
  int k   = rem >> 7;
  int o   = rem & 127;
  b16t[(size_t)(s * DOUT + o) * DIN + k] = (unsigned short)bf16rne(w[i]);
}

// ---- Fused dropout + bf16 MFMA GEMM (LDS XOR-swizzled) ----
// BM=64, BN=256 (all cols), BK=64. 512 threads = 8 waves (2x4 wave grid).
// Swizzle: u16 index ^= (row&7)<<3  (byte ^= (row&7)<<4) on As and Bs.
__global__ __launch_bounds__(512) void gemm_mfma(
    const float* __restrict__ x, const unsigned short* __restrict__ b16t,
    unsigned short* __restrict__ pre16) {
  __shared__ unsigned short As[64 * 64];    // [row][k]  8KB
  __shared__ unsigned short Bs[256 * 64];   // [col][k] 32KB
  const int t    = threadIdx.x;
  const int lane = t & 63;
  const int w    = t >> 6;
  const int wr   = w >> 2;
  const int wc   = w & 3;
  const int m0   = blockIdx.x * 64;

  f32x4 acc[2][4];
#pragma unroll
  for (int i = 0; i < 2; ++i)
#pragma unroll
    for (int j = 0; j < 4; ++j) acc[i][j] = (f32x4){0.f, 0.f, 0.f, 0.f};

  const int arow  = t >> 3;
  const int ak8   = (t & 7) * 8;
  const int agrow = m0 + arow;
  const int aswz  = (arow * 64 + ak8) ^ ((arow & 7) << 3);

  for (int kc = 0; kc < DIN; kc += 64) {
    __syncthreads();
    // A stage: fp32 load + threefry dropout + bf16 pack, 8 elems/thread
    {
      union { uint32_t u[4]; short8 s; } pk;
      if (agrow < N_NODES) {
        const float4* src = reinterpret_cast<const float4*>(
            x + (size_t)agrow * DIN + kc + ak8);
        float4 v0 = src[0], v1 = src[1];
        float f[8] = {v0.x, v0.y, v0.z, v0.w, v1.x, v1.y, v1.z, v1.w};
        uint32_t base = (uint32_t)(agrow * DIN + kc + ak8);
#pragma unroll
        for (int q = 0; q < 8; ++q)
          f[q] = keep_mask(base + q) ? f[q] * 2.0f : 0.0f;
#pragma unroll
        for (int q = 0; q < 4; ++q) pk.u[q] = pack_bf16x2(f[2 * q], f[2 * q + 1]);
      } else {
#pragma unroll
        for (int q = 0; q < 4; ++q) pk.u[q] = 0u;
      }
      *reinterpret_cast<short8*>(&As[aswz]) = pk.s;
    }
    // B stage: 256x64 bf16 from b16t, 4x16B per thread, swizzled store
#pragma unroll
    for (int i = 0; i < 4; ++i) {
      int c   = i * 512 + t;
      int col = c >> 3;
      int k8  = (c & 7) * 8;
      short8 v = *reinterpret_cast<const short8*>(
          b16t + (size_t)col * DIN + kc + k8);
      *reinterpret_cast<short8*>(&Bs[(col * 64 + k8) ^ ((col & 7) << 3)]) = v;
    }
    __syncthreads();

    short8 af[2][2], bf[2][4];
#pragma unroll
    for (int mf = 0; mf < 2; ++mf)
#pragma unroll
      for (int kk = 0; kk < 2; ++kk) {
        int row = wr * 32 + mf * 16 + (lane & 15);
        int idx = (row * 64 + kk * 32 + (lane >> 4) * 8) ^ ((row & 7) << 3);
        af[mf][kk] = *reinterpret_cast<const short8*>(&As[idx]);
      }
#pragma unroll
    for (int kk = 0; kk < 2; ++kk)
#pragma unroll
      for (int nf = 0; nf < 4; ++nf) {
        int col = wc * 64 + nf * 16 + (lane & 15);
        int idx = (col * 64 + kk * 32 + (lane >> 4) * 8) ^ ((col & 7) << 3);
        bf[kk][nf] = *reinterpret_cast<const short8*>(&Bs[idx]);
      }
#pragma unroll
    for (int mf = 0; mf < 2; ++mf)
#pragma unroll
      for (int nf = 0; nf < 4; ++nf)
#pragma unroll
        for (int kk = 0; kk < 2; ++kk)
          acc[mf][nf] = __builtin_amdgcn_mfma_f32_16x16x32_bf16(
              af[mf][kk], bf[kk][nf], acc[mf][nf], 0, 0, 0);
  }

  // epilogue: C/D layout col=lane&15, row=(lane>>4)*4+q (m89-verified)
#pragma unroll
  for (int mf = 0; mf < 2; ++mf) {
    int rbase = m0 + wr * 32 + mf * 16 + ((lane >> 4) * 4);
#pragma unroll
    for (int nf = 0; nf < 4; ++nf) {
      int col = wc * 64 + nf * 16 + (lane & 15);
      int s = col >> 7, o = col & 127;
#pragma unroll
      for (int q = 0; q < 4; ++q) {
        int row = rbase + q;
        if (row < N_NODES)
          pre16[(size_t)(s * N_NODES + row) * DOUT + o] =
              (unsigned short)bf16rne(acc[mf][nf][q]);
      }
    }
  }
}

// ---- bucket histogram (bucket = global_row >> 7) ----
__global__ __launch_bounds__(512) void count_b(const int* __restrict__ rows,
                                               int* __restrict__ gcnt) {
  __shared__ int hist[NB];
  int t = threadIdx.x;
  for (int b = t; b < NB; b += 512) hist[b] = 0;
  __syncthreads();
  int e0 = blockIdx.x * CH;
#pragma unroll
  for (int i = 0; i < EPT; ++i) {
    int e = e0 + i * 512 + t;
    if (e < NEDGE) {
      int s = (e >= EDGES) ? 1 : 0;
      int grow = s * N_NODES + rows[e];
      atomicAdd(&hist[grow >> 7], 1);
    }
  }
  __syncthreads();
  for (int b = t; b < NB; b += 512)
    if (hist[b]) atomicAdd(&gcnt[b], hist[b]);
}

// ---- exclusive scan of 782 bucket counts ----
__global__ __launch_bounds__(1024) void scan782(const int* __restrict__ gcnt,
                                                int* __restrict__ bstart,
                                                int* __restrict__ gcursor) {
  __shared__ int sm[1024];
  int t = threadIdx.x;
  int c = (t < NB) ? gcnt[t] : 0;
  sm[t] = c;
  __syncthreads();
  for (int d = 1; d < 1024; d <<= 1) {
    int v = sm[t];
    int a = (t >= d) ? sm[t - d] : 0;
    __syncthreads();
    sm[t] = v + a;
    __syncthreads();
  }
  if (t < NB) {
    int ex = sm[t] - c;
    bstart[t] = ex;
    gcursor[t] = ex;
  }
  if (t == NB - 1) bstart[NB] = sm[t];
}

// ---- LDS-binned scatter: edges -> binned[] grouped by bucket, coalesced flush ----
__global__ __launch_bounds__(512) void bin_scatter(
    const int* __restrict__ rows, const int* __restrict__ cols,
    const float* __restrict__ vals, int* __restrict__ gcursor,
    uint64_t* __restrict__ binned) {
  __shared__ uint32_t hist[NB];
  __shared__ uint32_t hexcl[NB];
  __shared__ uint32_t sbase[NB];
  __shared__ uint32_t scanb[512];
  __shared__ uint64_t ordered[CH];      // 64KB
  __shared__ uint16_t bk16[CH];         // 16KB
  int t = threadIdx.x;
  for (int b = t; b < NB; b += 512) hist[b] = 0;
  __syncthreads();
  int e0 = blockIdx.x * CH;
  uint32_t key[EPT], rank[EPT], bkt[EPT], vbits[EPT];
#pragma unroll
  for (int i = 0; i < EPT; ++i) {
    int e = e0 + i * 512 + t;
    if (e < NEDGE) {
      int s = (e >= EDGES) ? 1 : 0;
      uint32_t grow = (uint32_t)(s * N_NODES + rows[e]);
      uint32_t gcol = (uint32_t)(s * N_NODES + cols[e]);
      vbits[i] = __float_as_uint(vals[e]);
      uint32_t b = grow >> 7;
      bkt[i] = b;
      key[i] = ((grow & 127u) << 17) | gcol;
      rank[i] = atomicAdd(&hist[b], 1u);
    } else {
      bkt[i] = 0xFFFFFFFFu;
    }
  }
  __syncthreads();
  // exclusive scan of hist (2 entries per thread)
  int t2 = t * 2;
  uint32_t a0 = (t2 < NB) ? hist[t2] : 0u;
  uint32_t a1 = (t2 + 1 < NB) ? hist[t2 + 1] : 0u;
  scanb[t] = a0 + a1;
  __syncthreads();
  for (int d = 1; d < 512; d <<= 1) {
    uint32_t v = scanb[t];
    uint32_t a = (t >= d) ? scanb[t - d] : 0u;
    __syncthreads();
    scanb[t] = v + a;
    __syncthreads();
  }
  uint32_t base  = t ? scanb[t - 1] : 0u;
  uint32_t total = scanb[511];
  if (t2 < NB)     hexcl[t2]     = base;
  if (t2 + 1 < NB) hexcl[t2 + 1] = base + a0;
  // reserve global slots (one atomic per present bucket)
  for (int b = t; b < NB; b += 512)
    if (hist[b]) sbase[b] = (uint32_t)atomicAdd(&gcursor[b], (int)hist[b]);
  __syncthreads();
  // place into ordered LDS
#pragma unroll
  for (int i = 0; i < EPT; ++i) {
    if (bkt[i] != 0xFFFFFFFFu) {
      uint32_t slot = hexcl[bkt[i]] + rank[i];
      ordered[slot] = ((uint64_t)vbits[i] << 32) | key[i];
      bk16[slot] = (uint16_t)bkt[i];
    }
  }
  __syncthreads();
  // coalesced flush: consecutive slots -> mostly-consecutive global dst
#pragma unroll
  for (int i = 0; i < EPT; ++i) {
    uint32_t slot = (uint32_t)(i * 512 + t);
    if (slot < total) {
      uint32_t b = bk16[slot];
      uint32_t dst = sbase[b] + (slot - hexcl[b]);
      binned[dst] = ordered[slot];
    }
  }
}

// ---- push SpMM: block = 128-row bucket, LDS fp32 accumulator, fused ReLU ----
__global__ __launch_bounds__(512) void spmm_push(
    const int* __restrict__ bstart, const uint64_t* __restrict__ binned,
    const uint32_t* __restrict__ preu, float* __restrict__ out) {
  __shared__ float acc[128 * 128];      // 64KB
  const int t = threadIdx.x;
  const int b = blockIdx.x;
#pragma unroll
  for (int i = 0; i < 8; ++i)
    *reinterpret_cast<float4*>(&acc[(i * 512 + t) * 4]) =
        make_float4(0.f, 0.f, 0.f, 0.f);
  __syncthreads();
  const int lane = t & 63, wave = t >> 6;
  const int beg = bstart[b], end = bstart[b + 1];
  const int cnt = end - beg;
  int j    = beg + (cnt * wave) / 8;
  int wend = beg + (cnt * (wave + 1)) / 8;
  for (; j + 4 <= wend; j += 4) {
    uint64_t kv0 = binned[j], kv1 = binned[j + 1];
    uint64_t kv2 = binned[j + 2], kv3 = binned[j + 3];
    uint32_t k0 = (uint32_t)kv0, k1 = (uint32_t)kv1;
    uint32_t k2 = (uint32_t)kv2, k3 = (uint32_t)kv3;
    uint32_t p0 = preu[(size_t)(k0 & 0x1FFFFu) * 64 + lane];
    uint32_t p1 = preu[(size_t)(k1 & 0x1FFFFu) * 64 + lane];
    uint32_t p2 = preu[(size_t)(k2 & 0x1FFFFu) * 64 + lane];
    uint32_t p3 = preu[(size_t)(k3 & 0x1FFFFu) * 64 + lane];
    float v0 = __uint_as_float((uint32_t)(kv0 >> 32));
    float v1 = __uint_as_float((uint32_t)(kv1 >> 32));
    float v2 = __uint_as_float((uint32_t)(kv2 >> 32));
    float v3 = __uint_as_float((uint32_t)(kv3 >> 32));
    int c0 = 2 * lane;
    atomicAdd(&acc[(int)(k0 >> 17) * 128 + c0],     v0 * __uint_as_float(p0 << 16));
    atomicAdd(&acc[(int)(k0 >> 17) * 128 + c0 + 1], v0 * __uint_as_float(p0 & 0xffff0000u));
    atomicAdd(&acc[(int)(k1 >> 17) * 128 + c0],     v1 * __uint_as_float(p1 << 16));
    atomicAdd(&acc[(int)(k1 >> 17) * 128 + c0 + 1], v1 * __uint_as_float(p1 & 0xffff0000u));
    atomicAdd(&acc[(int)(k2 >> 17) * 128 + c0],     v2 * __uint_as_float(p2 << 16));
    atomicAdd(&acc[(int)(k2 >> 17) * 128 + c0 + 1], v2 * __uint_as_float(p2 & 0xffff0000u));
    atomicAdd(&acc[(int)(k3 >> 17) * 128 + c0],     v3 * __uint_as_float(p3 << 16));
    atomicAdd(&acc[(int)(k3 >> 17) * 128 + c0 + 1], v3 * __uint_as_float(p3 & 0xffff0000u));
  }
  for (; j < wend; ++j) {
    uint64_t kv = binned[j];
    uint32_t k = (uint32_t)kv;
    uint32_t p = preu[(size_t)(k & 0x1FFFFu) * 64 + lane];
    float v = __uint_as_float((uint32_t)(kv >> 32));
    int c0 = 2 * lane;
    atomicAdd(&acc[(int)(k >> 17) * 128 + c0],     v * __uint_as_float(p << 16));
    atomicAdd(&acc[(int)(k >> 17) * 128 + c0 + 1], v * __uint_as_float(p & 0xffff0000u));
  }
  __syncthreads();
  const int grow0 = b * 128;
#pragma unroll
  for (int i = 0; i < 8; ++i) {
    int idx = i * 512 + t;            // float4 units, 0..4095
    int r = idx >> 5, c4 = idx & 31;
    int grow = grow0 + r;
    if (grow < NROWS) {
      float4 v = *reinterpret_cast<float4*>(&acc[r * 128 + c4 * 4]);
      v.x = fmaxf(v.x, 0.f);
      v.y = fmaxf(v.y, 0.f);
      v.z = fmaxf(v.z, 0.f);
      v.w = fmaxf(v.w, 0.f);
      *reinterpret_cast<float4*>(&out[(size_t)grow * DOUT + c4 * 4]) = v;
    }
  }
}

extern "C" void kernel_launch(void* const* d_in, const int* in_sizes, int n_in,
                              void* d_out, int out_size, void* d_ws, size_t ws_size,
                              hipStream_t stream) {
  const float* x    = (const float*)d_in[0];
  const float* w    = (const float*)d_in[1];
  const int*   rows = (const int*)d_in[2];
  const int*   cols = (const int*)d_in[3];
  const float* vals = (const float*)d_in[4];
  float* out = (float*)d_out;

  // ws layout (u32 units)
  uint32_t* base = (uint32_t*)d_ws;
  uint32_t* preu = base;                                    // 6,400,000 (bf16 x2)
  unsigned short* b16t = (unsigned short*)(base + 6400000); // 65,536 u32
  int* gcnt    = (int*)(base + 6400000 + 65536);            // 800
  int* bstart  = gcnt + 800;                                // 800 (NB+1 used)
  int* gcursor = bstart + 800;                              // 800
  uint64_t* binned = (uint64_t*)(base + 6400000 + 65536 + 2400); // 1.6M u64
  size_t need = ((size_t)6400000 + 65536 + 2400 + 3200000) * 4;
  if (ws_size < need) return;  // loud fail

  hipMemsetAsync(gcnt, 0, NB * sizeof(int), stream);

  wcvt<<<(NSUP * DIN * DOUT + 255) / 256, 256, 0, stream>>>(w, b16t);

  gemm_mfma<<<(N_NODES + 63) / 64, 512, 0, stream>>>(x, b16t,
                                                     (unsigned short*)preu);

  count_b<<<NCH, 512, 0, stream>>>(rows, gcnt);
  scan782<<<1, 1024, 0, stream>>>(gcnt, bstart, gcursor);
  bin_scatter<<<NCH, 512, 0, stream>>>(rows, cols, vals, gcursor, binned);
  spmm_push<<<NB, 512, 0, stream>>>(bstart, binned, preu, out);
}

// Round 5
// 218.395 us; speedup vs baseline: 6.7260x; 6.7260x over previous
//
#include <hip/hip_runtime.h>
#include <stdint.h>

#define N_NODES 50000
#define DIN     512
#define DOUT    128
#define NSUP    2
#define EDGES   800000
#define NEDGE   (NSUP * EDGES)        // 1,600,000
#define NROWS   (NSUP * N_NODES)      // 100,000
#define NB      782                   // ceil(NROWS/128)
#define CH      8192                  // edges per bin_scatter block
#define NCH     ((NEDGE + CH - 1) / CH)   // 196
#define EPT     16                    // CH / 512 threads
#define SCAP    4096                  // sort_bucket LDS capacity (max bucket ~2300)

typedef __attribute__((ext_vector_type(8))) short short8;
typedef __attribute__((ext_vector_type(4))) float f32x4;

// ---- JAX threefry2x32, key(42) -> (0,42); partitionable, bits = o0^o1 (verified R1) ----
__device__ __forceinline__ uint32_t rotl32(uint32_t v, uint32_t d) {
  return (v << d) | (v >> (32u - d));
}

__device__ __forceinline__ void threefry2x32(uint32_t x0, uint32_t x1,
                                             uint32_t& o0, uint32_t& o1) {
  const uint32_t ks0 = 0u;
  const uint32_t ks1 = 42u;
  const uint32_t ks2 = 0u ^ 42u ^ 0x1BD11BDAu;
  x0 += ks0; x1 += ks1;
#define TF_R(r) { x0 += x1; x1 = rotl32(x1, (r)); x1 ^= x0; }
  TF_R(13) TF_R(15) TF_R(26) TF_R(6)
  x0 += ks1; x1 += ks2 + 1u;
  TF_R(17) TF_R(29) TF_R(16) TF_R(24)
  x0 += ks2; x1 += ks0 + 2u;
  TF_R(13) TF_R(15) TF_R(26) TF_R(6)
  x0 += ks0; x1 += ks1 + 3u;
  TF_R(17) TF_R(29) TF_R(16) TF_R(24)
  x0 += ks1; x1 += ks2 + 4u;
  TF_R(13) TF_R(15) TF_R(26) TF_R(6)
  x0 += ks2; x1 += ks0 + 5u;
#undef TF_R
  o0 = x0; o1 = x1;
}

__device__ __forceinline__ bool keep_mask(uint32_t idx) {
  uint32_t o0, o1;
  threefry2x32(0u, idx, o0, o1);
  uint32_t bits = o0 ^ o1;
  float u = __uint_as_float((bits >> 9) | 0x3F800000u) - 1.0f;
  return u < 0.5f;
}

__device__ __forceinline__ uint32_t pack_bf16x2(float a, float b) {
  uint32_t ua = __float_as_uint(a), ub = __float_as_uint(b);
  ua += 0x7fffu + ((ua >> 16) & 1u);
  ub += 0x7fffu + ((ub >> 16) & 1u);
  return (ua >> 16) | (ub & 0xffff0000u);
}

__device__ __forceinline__ uint32_t bf16rne(float f) {
  uint32_t u = __float_as_uint(f);
  u += 0x7fffu + ((u >> 16) & 1u);
  return u >> 16;
}

// ---- W [2][512][128] fp32 -> B16t [256 cols][512 k] bf16 (col = s*128+o) ----
__global__ __launch_bounds__(256) void wcvt(const float* __restrict__ w,
                                            unsigned short* __restrict__ b16t) {
  int i = blockIdx.x * 256 + threadIdx.x;
  if (i >= NSUP * DIN * DOUT) return;
  int s   = i >> 16;
  int rem = i & 65535;
  int k   = rem >> 7;
  int o   = rem & 127;
  b16t[(size_t)(s * DOUT + o) * DIN + k] = (unsigned short)bf16rne(w[i]);
}

// ---- Fused dropout + bf16 MFMA GEMM (LDS XOR-swizzled) ----
__global__ __launch_bounds__(512) void gemm_mfma(
    const float* __restrict__ x, const unsigned short* __restrict__ b16t,
    unsigned short* __restrict__ pre16) {
  __shared__ unsigned short As[64 * 64];    // 8KB
  __shared__ unsigned short Bs[256 * 64];   // 32KB
  const int t    = threadIdx.x;
  const int lane = t & 63;
  const int w    = t >> 6;
  const int wr   = w >> 2;
  const int wc   = w & 3;
  const int m0   = blockIdx.x * 64;

  f32x4 acc[2][4];
#pragma unroll
  for (int i = 0; i < 2; ++i)
#pragma unroll
    for (int j = 0; j < 4; ++j) acc[i][j] = (f32x4){0.f, 0.f, 0.f, 0.f};

  const int arow  = t >> 3;
  const int ak8   = (t & 7) * 8;
  const int agrow = m0 + arow;
  const int aswz  = (arow * 64 + ak8) ^ ((arow & 7) << 3);

  for (int kc = 0; kc < DIN; kc += 64) {
    __syncthreads();
    {
      union { uint32_t u[4]; short8 s; } pk;
      if (agrow < N_NODES) {
        const float4* src = reinterpret_cast<const float4*>(
            x + (size_t)agrow * DIN + kc + ak8);
        float4 v0 = src[0], v1 = src[1];
        float f[8] = {v0.x, v0.y, v0.z, v0.w, v1.x, v1.y, v1.z, v1.w};
        uint32_t base = (uint32_t)(agrow * DIN + kc + ak8);
#pragma unroll
        for (int q = 0; q < 8; ++q)
          f[q] = keep_mask(base + q) ? f[q] * 2.0f : 0.0f;
#pragma unroll
        for (int q = 0; q < 4; ++q) pk.u[q] = pack_bf16x2(f[2 * q], f[2 * q + 1]);
      } else {
#pragma unroll
        for (int q = 0; q < 4; ++q) pk.u[q] = 0u;
      }
      *reinterpret_cast<short8*>(&As[aswz]) = pk.s;
    }
#pragma unroll
    for (int i = 0; i < 4; ++i) {
      int c   = i * 512 + t;
      int col = c >> 3;
      int k8  = (c & 7) * 8;
      short8 v = *reinterpret_cast<const short8*>(
          b16t + (size_t)col * DIN + kc + k8);
      *reinterpret_cast<short8*>(&Bs[(col * 64 + k8) ^ ((col & 7) << 3)]) = v;
    }
    __syncthreads();

    short8 af[2][2], bf[2][4];
#pragma unroll
    for (int mf = 0; mf < 2; ++mf)
#pragma unroll
      for (int kk = 0; kk < 2; ++kk) {
        int row = wr * 32 + mf * 16 + (lane & 15);
        int idx = (row * 64 + kk * 32 + (lane >> 4) * 8) ^ ((row & 7) << 3);
        af[mf][kk] = *reinterpret_cast<const short8*>(&As[idx]);
      }
#pragma unroll
    for (int kk = 0; kk < 2; ++kk)
#pragma unroll
      for (int nf = 0; nf < 4; ++nf) {
        int col = wc * 64 + nf * 16 + (lane & 15);
        int idx = (col * 64 + kk * 32 + (lane >> 4) * 8) ^ ((col & 7) << 3);
        bf[kk][nf] = *reinterpret_cast<const short8*>(&Bs[idx]);
      }
#pragma unroll
    for (int mf = 0; mf < 2; ++mf)
#pragma unroll
      for (int nf = 0; nf < 4; ++nf)
#pragma unroll
        for (int kk = 0; kk < 2; ++kk)
          acc[mf][nf] = __builtin_amdgcn_mfma_f32_16x16x32_bf16(
              af[mf][kk], bf[kk][nf], acc[mf][nf], 0, 0, 0);
  }

#pragma unroll
  for (int mf = 0; mf < 2; ++mf) {
    int rbase = m0 + wr * 32 + mf * 16 + ((lane >> 4) * 4);
#pragma unroll
    for (int nf = 0; nf < 4; ++nf) {
      int col = wc * 64 + nf * 16 + (lane & 15);
      int s = col >> 7, o = col & 127;
#pragma unroll
      for (int q = 0; q < 4; ++q) {
        int row = rbase + q;
        if (row < N_NODES)
          pre16[(size_t)(s * N_NODES + row) * DOUT + o] =
              (unsigned short)bf16rne(acc[mf][nf][q]);
      }
    }
  }
}

// ---- bucket histogram (bucket = global_row >> 7) ----
__global__ __launch_bounds__(512) void count_b(const int* __restrict__ rows,
                                               int* __restrict__ gcnt) {
  __shared__ int hist[NB];
  int t = threadIdx.x;
  for (int b = t; b < NB; b += 512) hist[b] = 0;
  __syncthreads();
  int e0 = blockIdx.x * CH;
#pragma unroll
  for (int i = 0; i < EPT; ++i) {
    int e = e0 + i * 512 + t;
    if (e < NEDGE) {
      int s = (e >= EDGES) ? 1 : 0;
      int grow = s * N_NODES + rows[e];
      atomicAdd(&hist[grow >> 7], 1);
    }
  }
  __syncthreads();
  for (int b = t; b < NB; b += 512)
    if (hist[b]) atomicAdd(&gcnt[b], hist[b]);
}

// ---- exclusive scan of 782 bucket counts ----
__global__ __launch_bounds__(1024) void scan782(const int* __restrict__ gcnt,
                                                int* __restrict__ bstart,
                                                int* __restrict__ gcursor) {
  __shared__ int sm[1024];
  int t = threadIdx.x;
  int c = (t < NB) ? gcnt[t] : 0;
  sm[t] = c;
  __syncthreads();
  for (int d = 1; d < 1024; d <<= 1) {
    int v = sm[t];
    int a = (t >= d) ? sm[t - d] : 0;
    __syncthreads();
    sm[t] = v + a;
    __syncthreads();
  }
  if (t < NB) {
    int ex = sm[t] - c;
    bstart[t] = ex;
    gcursor[t] = ex;
  }
  if (t == NB - 1) bstart[NB] = sm[t];
}

// ---- LDS-binned scatter: edges -> binned[] grouped by bucket, coalesced flush ----
__global__ __launch_bounds__(512) void bin_scatter(
    const int* __restrict__ rows, const int* __restrict__ cols,
    const float* __restrict__ vals, int* __restrict__ gcursor,
    uint64_t* __restrict__ binned) {
  __shared__ uint32_t hist[NB];
  __shared__ uint32_t hexcl[NB];
  __shared__ uint32_t sbase[NB];
  __shared__ uint32_t scanb[512];
  __shared__ uint64_t ordered[CH];      // 64KB
  __shared__ uint16_t bk16[CH];         // 16KB
  int t = threadIdx.x;
  for (int b = t; b < NB; b += 512) hist[b] = 0;
  __syncthreads();
  int e0 = blockIdx.x * CH;
  uint32_t key[EPT], rank[EPT], bkt[EPT], vbits[EPT];
#pragma unroll
  for (int i = 0; i < EPT; ++i) {
    int e = e0 + i * 512 + t;
    if (e < NEDGE) {
      int s = (e >= EDGES) ? 1 : 0;
      uint32_t grow = (uint32_t)(s * N_NODES + rows[e]);
      uint32_t gcol = (uint32_t)(s * N_NODES + cols[e]);
      vbits[i] = __float_as_uint(vals[e]);
      uint32_t b = grow >> 7;
      bkt[i] = b;
      key[i] = ((grow & 127u) << 17) | gcol;
      rank[i] = atomicAdd(&hist[b], 1u);
    } else {
      bkt[i] = 0xFFFFFFFFu;
    }
  }
  __syncthreads();
  int t2 = t * 2;
  uint32_t a0 = (t2 < NB) ? hist[t2] : 0u;
  uint32_t a1 = (t2 + 1 < NB) ? hist[t2 + 1] : 0u;
  scanb[t] = a0 + a1;
  __syncthreads();
  for (int d = 1; d < 512; d <<= 1) {
    uint32_t v = scanb[t];
    uint32_t a = (t >= d) ? scanb[t - d] : 0u;
    __syncthreads();
    scanb[t] = v + a;
    __syncthreads();
  }
  uint32_t base  = t ? scanb[t - 1] : 0u;
  uint32_t total = scanb[511];
  if (t2 < NB)     hexcl[t2]     = base;
  if (t2 + 1 < NB) hexcl[t2 + 1] = base + a0;
  for (int b = t; b < NB; b += 512)
    if (hist[b]) sbase[b] = (uint32_t)atomicAdd(&gcursor[b], (int)hist[b]);
  __syncthreads();
#pragma unroll
  for (int i = 0; i < EPT; ++i) {
    if (bkt[i] != 0xFFFFFFFFu) {
      uint32_t slot = hexcl[bkt[i]] + rank[i];
      ordered[slot] = ((uint64_t)vbits[i] << 32) | key[i];
      bk16[slot] = (uint16_t)bkt[i];
    }
  }
  __syncthreads();
#pragma unroll
  for (int i = 0; i < EPT; ++i) {
    uint32_t slot = (uint32_t)(i * 512 + t);
    if (slot < total) {
      uint32_t b = bk16[slot];
      uint32_t dst = sbase[b] + (slot - hexcl[b]);
      binned[dst] = ordered[slot];
    }
  }
}

// ---- per-bucket counting sort by row-in-bucket, in place; emits row_start ----
__global__ __launch_bounds__(512) void sort_bucket(
    const int* __restrict__ bstart, uint64_t* __restrict__ binned,
    int* __restrict__ row_start) {
  __shared__ uint64_t ordered[SCAP];    // 32KB
  __shared__ uint32_t hist[128];
  __shared__ uint32_t excl[128];
  const int t = threadIdx.x;
  const int b = blockIdx.x;
  const int beg = bstart[b], end = bstart[b + 1];
  const int cnt = end - beg;
  if (t < 128) hist[t] = 0;
  __syncthreads();
  uint64_t ed[8];
  uint32_t rk[8], rw[8];
#pragma unroll
  for (int i = 0; i < 8; ++i) {
    int slot = i * 512 + t;
    if (slot < cnt) {
      uint64_t e = binned[beg + slot];
      ed[i] = e;
      uint32_t rowin = ((uint32_t)e >> 17) & 127u;
      rw[i] = rowin;
      rk[i] = atomicAdd(&hist[rowin], 1u);
    } else {
      rw[i] = 0xFFFFFFFFu;
    }
  }
  __syncthreads();
  // Hillis-Steele inclusive scan over 128 bins, then convert to exclusive
  if (t < 128) excl[t] = hist[t];
  __syncthreads();
  for (int d = 1; d < 128; d <<= 1) {
    uint32_t v = (t < 128) ? excl[t] : 0u;
    uint32_t a = (t >= d && t < 128) ? excl[t - d] : 0u;
    __syncthreads();
    if (t < 128) excl[t] = v + a;
    __syncthreads();
  }
  if (t < 128) {
    uint32_t ex = excl[t] - hist[t];
    int grow = b * 128 + t;
    if (grow < NROWS) row_start[grow] = beg + (int)ex;
    excl[t] = ex;
  }
  __syncthreads();
#pragma unroll
  for (int i = 0; i < 8; ++i)
    if (rw[i] != 0xFFFFFFFFu)
      ordered[excl[rw[i]] + rk[i]] = ed[i];
  __syncthreads();
#pragma unroll
  for (int i = 0; i < 8; ++i) {
    int slot = i * 512 + t;
    if (slot < cnt) binned[beg + slot] = ordered[slot];
  }
  if (b == 0 && t == 0) row_start[NROWS] = NEDGE;
}

// ---- Pull SpMM + ReLU: 1 wave/row, lane owns cols {2l,2l+1}, 4x unrolled ----
__global__ __launch_bounds__(256) void spmm_pull(
    const int* __restrict__ row_start, const uint64_t* __restrict__ binned,
    const uint32_t* __restrict__ preu, float* __restrict__ out) {
  int rid  = blockIdx.x * 4 + (threadIdx.x >> 6);
  int lane = threadIdx.x & 63;
  if (rid >= NROWS) return;
  int beg = row_start[rid];
  int end = row_start[rid + 1];
  float a0 = 0.f, a1 = 0.f;
  int j = beg;
  for (; j + 4 <= end; j += 4) {
    uint64_t e0 = binned[j],     e1 = binned[j + 1];
    uint64_t e2 = binned[j + 2], e3 = binned[j + 3];
    uint32_t q0 = preu[(size_t)((uint32_t)e0 & 0x1FFFFu) * 64 + lane];
    uint32_t q1 = preu[(size_t)((uint32_t)e1 & 0x1FFFFu) * 64 + lane];
    uint32_t q2 = preu[(size_t)((uint32_t)e2 & 0x1FFFFu) * 64 + lane];
    uint32_t q3 = preu[(size_t)((uint32_t)e3 & 0x1FFFFu) * 64 + lane];
    float v0 = __uint_as_float((uint32_t)(e0 >> 32));
    float v1 = __uint_as_float((uint32_t)(e1 >> 32));
    float v2 = __uint_as_float((uint32_t)(e2 >> 32));
    float v3 = __uint_as_float((uint32_t)(e3 >> 32));
    a0 += v0 * __uint_as_float(q0 << 16);
    a1 += v0 * __uint_as_float(q0 & 0xffff0000u);
    a0 += v1 * __uint_as_float(q1 << 16);
    a1 += v1 * __uint_as_float(q1 & 0xffff0000u);
    a0 += v2 * __uint_as_float(q2 << 16);
    a1 += v2 * __uint_as_float(q2 & 0xffff0000u);
    a0 += v3 * __uint_as_float(q3 << 16);
    a1 += v3 * __uint_as_float(q3 & 0xffff0000u);
  }
  for (; j < end; ++j) {
    uint64_t e = binned[j];
    uint32_t q = preu[(size_t)((uint32_t)e & 0x1FFFFu) * 64 + lane];
    float v = __uint_as_float((uint32_t)(e >> 32));
    a0 += v * __uint_as_float(q << 16);
    a1 += v * __uint_as_float(q & 0xffff0000u);
  }
  float2 o = make_float2(fmaxf(a0, 0.f), fmaxf(a1, 0.f));
  *reinterpret_cast<float2*>(out + (size_t)rid * DOUT + 2 * lane) = o;
}

extern "C" void kernel_launch(void* const* d_in, const int* in_sizes, int n_in,
                              void* d_out, int out_size, void* d_ws, size_t ws_size,
                              hipStream_t stream) {
  const float* x    = (const float*)d_in[0];
  const float* w    = (const float*)d_in[1];
  const int*   rows = (const int*)d_in[2];
  const int*   cols = (const int*)d_in[3];
  const float* vals = (const float*)d_in[4];
  float* out = (float*)d_out;

  // ws layout (u32 units)
  uint32_t* base = (uint32_t*)d_ws;
  uint32_t* preu = base;                                    // 6,400,000 (bf16 x2)
  unsigned short* b16t = (unsigned short*)(base + 6400000); // 65,536 u32
  int* gcnt      = (int*)(base + 6400000 + 65536);          // 800
  int* bstart    = gcnt + 800;                              // 800 (NB+1 used)
  int* gcursor   = bstart + 800;                            // 800
  int* row_start = gcursor + 800;                           // 100,004
  uint64_t* binned = (uint64_t*)(row_start + 100004);       // 1.6M x 8B
  size_t need = ((size_t)6400000 + 65536 + 2400 + 100004 + 3200000) * 4;
  if (ws_size < need) return;  // loud fail

  hipMemsetAsync(gcnt, 0, NB * sizeof(int), stream);

  wcvt<<<(NSUP * DIN * DOUT + 255) / 256, 256, 0, stream>>>(w, b16t);

  gemm_mfma<<<(N_NODES + 63) / 64, 512, 0, stream>>>(x, b16t,
                                                     (unsigned short*)preu);

  count_b<<<NCH, 512, 0, stream>>>(rows, gcnt);
  scan782<<<1, 1024, 0, stream>>>(gcnt, bstart, gcursor);
  bin_scatter<<<NCH, 512, 0, stream>>>(rows, cols, vals, gcursor, binned);
  sort_bucket<<<NB, 512, 0, stream>>>(bstart, binned, row_start);

  spmm_pull<<<(NROWS + 3) / 4, 256, 0, stream>>>(row_start, binned, preu, out);
}

// Round 7
// 216.832 us; speedup vs baseline: 6.7745x; 1.0072x over previous
//
#include <hip/hip_runtime.h>
#include <stdint.h>

#define N_NODES 50000
#define DIN     512
#define DOUT    128
#define NSUP    2
#define EDGES   800000
#define NEDGE   (NSUP * EDGES)        // 1,600,000
#define NROWS   (NSUP * N_NODES)      // 100,000
#define NB      782                   // ceil(NROWS/128)
#define CH      8192                  // edges per bin_scatter block
#define NCH     ((NEDGE + CH - 1) / CH)   // 196
#define EPT     16                    // CH / 512 threads
#define SCAP    4096                  // sort_bucket LDS capacity (max bucket ~2300)
#define NMASKW  ((N_NODES * DIN) / 32)    // 800,000 mask words

typedef __attribute__((ext_vector_type(8))) short short8;
typedef __attribute__((ext_vector_type(4))) float f32x4;

// ---- JAX threefry2x32, key(42) -> (0,42); partitionable, bits = o0^o1 (verified R1) ----
__device__ __forceinline__ uint32_t rotl32(uint32_t v, uint32_t d) {
  return (v << d) | (v >> (32u - d));
}

__device__ __forceinline__ void threefry2x32(uint32_t x0, uint32_t x1,
                                             uint32_t& o0, uint32_t& o1) {
  const uint32_t ks0 = 0u;
  const uint32_t ks1 = 42u;
  const uint32_t ks2 = 0u ^ 42u ^ 0x1BD11BDAu;
  x0 += ks0; x1 += ks1;
#define TF_R(r) { x0 += x1; x1 = rotl32(x1, (r)); x1 ^= x0; }
  TF_R(13) TF_R(15) TF_R(26) TF_R(6)
  x0 += ks1; x1 += ks2 + 1u;
  TF_R(17) TF_R(29) TF_R(16) TF_R(24)
  x0 += ks2; x1 += ks0 + 2u;
  TF_R(13) TF_R(15) TF_R(26) TF_R(6)
  x0 += ks0; x1 += ks1 + 3u;
  TF_R(17) TF_R(29) TF_R(16) TF_R(24)
  x0 += ks1; x1 += ks2 + 4u;
  TF_R(13) TF_R(15) TF_R(26) TF_R(6)
  x0 += ks2; x1 += ks0 + 5u;
#undef TF_R
  o0 = x0; o1 = x1;
}

__device__ __forceinline__ bool keep_mask(uint32_t idx) {
  uint32_t o0, o1;
  threefry2x32(0u, idx, o0, o1);
  uint32_t bits = o0 ^ o1;
  float u = __uint_as_float((bits >> 9) | 0x3F800000u) - 1.0f;
  return u < 0.5f;
}

__device__ __forceinline__ uint32_t pack_bf16x2(float a, float b) {
  uint32_t ua = __float_as_uint(a), ub = __float_as_uint(b);
  ua += 0x7fffu + ((ua >> 16) & 1u);
  ub += 0x7fffu + ((ub >> 16) & 1u);
  return (ua >> 16) | (ub & 0xffff0000u);
}

__device__ __forceinline__ uint32_t bf16rne(float f) {
  uint32_t u = __float_as_uint(f);
  u += 0x7fffu + ((u >> 16) & 1u);
  return u >> 16;
}

// ---- dropout mask: word w holds keep-bits for elems 32w..32w+31 ----
__global__ __launch_bounds__(256) void maskgen(uint32_t* __restrict__ maskbuf) {
  int wid = blockIdx.x * 256 + threadIdx.x;
  if (wid >= NMASKW) return;
  uint32_t base = (uint32_t)wid * 32u;
  uint32_t m = 0u;
#pragma unroll 4
  for (int q = 0; q < 32; ++q)
    m |= (keep_mask(base + q) ? 1u : 0u) << q;
  maskbuf[wid] = m;
}

// ---- W [2][512][128] fp32 -> B16t [256 cols][512 k] bf16 (col = s*128+o) ----
__global__ __launch_bounds__(256) void wcvt(const float* __restrict__ w,
                                            unsigned short* __restrict__ b16t) {
  int i = blockIdx.x * 256 + threadIdx.x;
  if (i >= NSUP * DIN * DOUT) return;
  int s   = i >> 16;
  int rem = i & 65535;
  int k   = rem >> 7;
  int o   = rem & 127;
  b16t[(size_t)(s * DOUT + o) * DIN + k] = (unsigned short)bf16rne(w[i]);
}

// ---- bf16 MFMA GEMM with fused mask-apply: BM=128, BN=256, BK=64 ----
// 512 threads = 8 waves (2x4): wave (wr,wc) owns rows wr*64..+63, cols wc*64..+63
// -> 4x4 frags of 16x16x32. XOR swizzle: u16 idx ^= (row&7)<<3.
__global__ __launch_bounds__(512) void gemm_mfma2(
    const float* __restrict__ x, const uint32_t* __restrict__ maskbuf,
    const unsigned short* __restrict__ b16t,
    unsigned short* __restrict__ pre16) {
  __shared__ unsigned short As[128 * 64];   // 16KB
  __shared__ unsigned short Bs[256 * 64];   // 32KB
  const int t    = threadIdx.x;
  const int lane = t & 63;
  const int w    = t >> 6;
  const int wr   = w >> 2;
  const int wc   = w & 3;
  const int m0   = blockIdx.x * 128;

  f32x4 acc[4][4];
#pragma unroll
  for (int i = 0; i < 4; ++i)
#pragma unroll
    for (int j = 0; j < 4; ++j) acc[i][j] = (f32x4){0.f, 0.f, 0.f, 0.f};

  for (int kc = 0; kc < DIN; kc += 64) {
    __syncthreads();
    // A stage: 128 rows x 64 k of x fp32 + mask-apply + bf16 pack; 2 slots/thread
#pragma unroll
    for (int i = 0; i < 2; ++i) {
      int slot = i * 512 + t;
      int row  = slot >> 3;
      int k8   = (slot & 7) * 8;
      int grow = m0 + row;
      union { uint32_t u[4]; short8 s; } pk;
      if (grow < N_NODES) {
        uint32_t b8 = (uint32_t)grow * DIN + (uint32_t)(kc + k8);
        const float4* src = reinterpret_cast<const float4*>(x + b8);
        float4 v0 = src[0], v1 = src[1];
        float f[8] = {v0.x, v0.y, v0.z, v0.w, v1.x, v1.y, v1.z, v1.w};
        uint32_t bits = maskbuf[b8 >> 5] >> (b8 & 31u);
#pragma unroll
        for (int q = 0; q < 8; ++q)
          f[q] = ((bits >> q) & 1u) ? f[q] * 2.0f : 0.0f;
#pragma unroll
        for (int q = 0; q < 4; ++q) pk.u[q] = pack_bf16x2(f[2 * q], f[2 * q + 1]);
      } else {
#pragma unroll
        for (int q = 0; q < 4; ++q) pk.u[q] = 0u;
      }
      *reinterpret_cast<short8*>(&As[(row * 64 + k8) ^ ((row & 7) << 3)]) = pk.s;
    }
    // B stage: 256x64 bf16 = 2048 short8 slots, 4 per thread
#pragma unroll
    for (int i = 0; i < 4; ++i) {
      int slot = i * 512 + t;
      int col  = slot >> 3;
      int k8   = (slot & 7) * 8;
      short8 v = *reinterpret_cast<const short8*>(
          b16t + (size_t)col * DIN + kc + k8);
      *reinterpret_cast<short8*>(&Bs[(col * 64 + k8) ^ ((col & 7) << 3)]) = v;
    }
    __syncthreads();

    short8 af[4][2], bf[2][4];
#pragma unroll
    for (int mf = 0; mf < 4; ++mf)
#pragma unroll
      for (int kk = 0; kk < 2; ++kk) {
        int row = wr * 64 + mf * 16 + (lane & 15);
        int idx = (row * 64 + kk * 32 + (lane >> 4) * 8) ^ ((row & 7) << 3);
        af[mf][kk] = *reinterpret_cast<const short8*>(&As[idx]);
      }
#pragma unroll
    for (int kk = 0; kk < 2; ++kk)
#pragma unroll
      for (int nf = 0; nf < 4; ++nf) {
        int col = wc * 64 + nf * 16 + (lane & 15);
        int idx = (col * 64 + kk * 32 + (lane >> 4) * 8) ^ ((col & 7) << 3);
        bf[kk][nf] = *reinterpret_cast<const short8*>(&Bs[idx]);
      }
#pragma unroll
    for (int mf = 0; mf < 4; ++mf)
#pragma unroll
      for (int nf = 0; nf < 4; ++nf)
#pragma unroll
        for (int kk = 0; kk < 2; ++kk)
          acc[mf][nf] = __builtin_amdgcn_mfma_f32_16x16x32_bf16(
              af[mf][kk], bf[kk][nf], acc[mf][nf], 0, 0, 0);
  }

  // epilogue: C/D layout col=lane&15, row=(lane>>4)*4+q (m89-verified)
#pragma unroll
  for (int mf = 0; mf < 4; ++mf) {
    int rbase = m0 + wr * 64 + mf * 16 + ((lane >> 4) * 4);
#pragma unroll
    for (int nf = 0; nf < 4; ++nf) {
      int col = wc * 64 + nf * 16 + (lane & 15);
      int s = col >> 7, o = col & 127;
#pragma unroll
      for (int q = 0; q < 4; ++q) {
        int row = rbase + q;
        if (row < N_NODES)
          pre16[(size_t)(s * N_NODES + row) * DOUT + o] =
              (unsigned short)bf16rne(acc[mf][nf][q]);
      }
    }
  }
}

// ---- bucket histogram (bucket = global_row >> 7) ----
__global__ __launch_bounds__(512) void count_b(const int* __restrict__ rows,
                                               int* __restrict__ gcnt) {
  __shared__ int hist[NB];
  int t = threadIdx.x;
  for (int b = t; b < NB; b += 512) hist[b] = 0;
  __syncthreads();
  int e0 = blockIdx.x * CH;
#pragma unroll
  for (int i = 0; i < EPT; ++i) {
    int e = e0 + i * 512 + t;
    if (e < NEDGE) {
      int s = (e >= EDGES) ? 1 : 0;
      int grow = s * N_NODES + rows[e];
      atomicAdd(&hist[grow >> 7], 1);
    }
  }
  __syncthreads();
  for (int b = t; b < NB; b += 512)
    if (hist[b]) atomicAdd(&gcnt[b], hist[b]);
}

// ---- exclusive scan of 782 bucket counts ----
__global__ __launch_bounds__(1024) void scan782(const int* __restrict__ gcnt,
                                                int* __restrict__ bstart,
                                                int* __restrict__ gcursor) {
  __shared__ int sm[1024];
  int t = threadIdx.x;
  int c = (t < NB) ? gcnt[t] : 0;
  sm[t] = c;
  __syncthreads();
  for (int d = 1; d < 1024; d <<= 1) {
    int v = sm[t];
    int a = (t >= d) ? sm[t - d] : 0;
    __syncthreads();
    sm[t] = v + a;
    __syncthreads();
  }
  if (t < NB) {
    int ex = sm[t] - c;
    bstart[t] = ex;
    gcursor[t] = ex;
  }
  if (t == NB - 1) bstart[NB] = sm[t];
}

// ---- LDS-binned scatter: edges -> binned[] grouped by bucket, coalesced flush ----
__global__ __launch_bounds__(512) void bin_scatter(
    const int* __restrict__ rows, const int* __restrict__ cols,
    const float* __restrict__ vals, int* __restrict__ gcursor,
    uint64_t* __restrict__ binned) {
  __shared__ uint32_t hist[NB];
  __shared__ uint32_t hexcl[NB];
  __shared__ uint32_t sbase[NB];
  __shared__ uint32_t scanb[512];
  __shared__ uint64_t ordered[CH];      // 64KB
  __shared__ uint16_t bk16[CH];         // 16KB
  int t = threadIdx.x;
  for (int b = t; b < NB; b += 512) hist[b] = 0;
  __syncthreads();
  int e0 = blockIdx.x * CH;
  uint32_t key[EPT], rank[EPT], bkt[EPT], vbits[EPT];
#pragma unroll
  for (int i = 0; i < EPT; ++i) {
    int e = e0 + i * 512 + t;
    if (e < NEDGE) {
      int s = (e >= EDGES) ? 1 : 0;
      uint32_t grow = (uint32_t)(s * N_NODES + rows[e]);
      uint32_t gcol = (uint32_t)(s * N_NODES + cols[e]);
      vbits[i] = __float_as_uint(vals[e]);
      uint32_t b = grow >> 7;
      bkt[i] = b;
      key[i] = ((grow & 127u) << 17) | gcol;
      rank[i] = atomicAdd(&hist[b], 1u);
    } else {
      bkt[i] = 0xFFFFFFFFu;
    }
  }
  __syncthreads();
  int t2 = t * 2;
  uint32_t a0 = (t2 < NB) ? hist[t2] : 0u;
  uint32_t a1 = (t2 + 1 < NB) ? hist[t2 + 1] : 0u;
  scanb[t] = a0 + a1;
  __syncthreads();
  for (int d = 1; d < 512; d <<= 1) {
    uint32_t v = scanb[t];
    uint32_t a = (t >= d) ? scanb[t - d] : 0u;
    __syncthreads();
    scanb[t] = v + a;
    __syncthreads();
  }
  uint32_t base  = t ? scanb[t - 1] : 0u;
  uint32_t total = scanb[511];
  if (t2 < NB)     hexcl[t2]     = base;
  if (t2 + 1 < NB) hexcl[t2 + 1] = base + a0;
  for (int b = t; b < NB; b += 512)
    if (hist[b]) sbase[b] = (uint32_t)atomicAdd(&gcursor[b], (int)hist[b]);
  __syncthreads();
#pragma unroll
  for (int i = 0; i < EPT; ++i) {
    if (bkt[i] != 0xFFFFFFFFu) {
      uint32_t slot = hexcl[bkt[i]] + rank[i];
      ordered[slot] = ((uint64_t)vbits[i] << 32) | key[i];
      bk16[slot] = (uint16_t)bkt[i];
    }
  }
  __syncthreads();
#pragma unroll
  for (int i = 0; i < EPT; ++i) {
    uint32_t slot = (uint32_t)(i * 512 + t);
    if (slot < total) {
      uint32_t b = bk16[slot];
      uint32_t dst = sbase[b] + (slot - hexcl[b]);
      binned[dst] = ordered[slot];
    }
  }
}

// ---- per-bucket counting sort by row-in-bucket, in place; emits row_start ----
__global__ __launch_bounds__(512) void sort_bucket(
    const int* __restrict__ bstart, uint64_t* __restrict__ binned,
    int* __restrict__ row_start) {
  __shared__ uint64_t ordered[SCAP];    // 32KB
  __shared__ uint32_t hist[128];
  __shared__ uint32_t excl[128];
  const int t = threadIdx.x;
  const int b = blockIdx.x;
  const int beg = bstart[b], end = bstart[b + 1];
  const int cnt = end - beg;
  if (t < 128) hist[t] = 0;
  __syncthreads();
  uint64_t ed[8];
  uint32_t rk[8], rw[8];
#pragma unroll
  for (int i = 0; i < 8; ++i) {
    int slot = i * 512 + t;
    if (slot < cnt) {
      uint64_t e = binned[beg + slot];
      ed[i] = e;
      uint32_t rowin = ((uint32_t)e >> 17) & 127u;
      rw[i] = rowin;
      rk[i] = atomicAdd(&hist[rowin], 1u);
    } else {
      rw[i] = 0xFFFFFFFFu;
    }
  }
  __syncthreads();
  if (t < 128) excl[t] = hist[t];
  __syncthreads();
  for (int d = 1; d < 128; d <<= 1) {
    uint32_t v = (t < 128) ? excl[t] : 0u;
    uint32_t a = (t >= d && t < 128) ? excl[t - d] : 0u;
    __syncthreads();
    if (t < 128) excl[t] = v + a;
    __syncthreads();
  }
  if (t < 128) {
    uint32_t ex = excl[t] - hist[t];
    int grow = b * 128 + t;
    if (grow < NROWS) row_start[grow] = beg + (int)ex;
    excl[t] = ex;
  }
  __syncthreads();
#pragma unroll
  for (int i = 0; i < 8; ++i)
    if (rw[i] != 0xFFFFFFFFu)
      ordered[excl[rw[i]] + rk[i]] = ed[i];
  __syncthreads();
#pragma unroll
  for (int i = 0; i < 8; ++i) {
    int slot = i * 512 + t;
    if (slot < cnt) binned[beg + slot] = ordered[slot];
  }
  if (b == 0 && t == 0) row_start[NROWS] = NEDGE;
}

// ---- Pull SpMM + ReLU: 1 wave/row, lane owns cols {2l,2l+1}, 4x unrolled ----
__global__ __launch_bounds__(256) void spmm_pull(
    const int* __restrict__ row_start, const uint64_t* __restrict__ binned,
    const uint32_t* __restrict__ preu, float* __restrict__ out) {
  int rid  = blockIdx.x * 4 + (threadIdx.x >> 6);
  int lane = threadIdx.x & 63;
  if (rid >= NROWS) return;
  int beg = row_start[rid];
  int end = row_start[rid + 1];
  float a0 = 0.f, a1 = 0.f;
  int j = beg;
  for (; j + 4 <= end; j += 4) {
    uint64_t e0 = binned[j],     e1 = binned[j + 1];
    uint64_t e2 = binned[j + 2], e3 = binned[j + 3];
    uint32_t q0 = preu[(size_t)((uint32_t)e0 & 0x1FFFFu) * 64 + lane];
    uint32_t q1 = preu[(size_t)((uint32_t)e1 & 0x1FFFFu) * 64 + lane];
    uint32_t q2 = preu[(size_t)((uint32_t)e2 & 0x1FFFFu) * 64 + lane];
    uint32_t q3 = preu[(size_t)((uint32_t)e3 & 0x1FFFFu) * 64 + lane];
    float v0 = __uint_as_float((uint32_t)(e0 >> 32));
    float v1 = __uint_as_float((uint32_t)(e1 >> 32));
    float v2 = __uint_as_float((uint32_t)(e2 >> 32));
    float v3 = __uint_as_float((uint32_t)(e3 >> 32));
    a0 += v0 * __uint_as_float(q0 << 16);
    a1 += v0 * __uint_as_float(q0 & 0xffff0000u);
    a0 += v1 * __uint_as_float(q1 << 16);
    a1 += v1 * __uint_as_float(q1 & 0xffff0000u);
    a0 += v2 * __uint_as_float(q2 << 16);
    a1 += v2 * __uint_as_float(q2 & 0xffff0000u);
    a0 += v3 * __uint_as_float(q3 << 16);
    a1 += v3 * __uint_as_float(q3 & 0xffff0000u);
  }
  for (; j < end; ++j) {
    uint64_t e = binned[j];
    uint32_t q = preu[(size_t)((uint32_t)e & 0x1FFFFu) * 64 + lane];
    float v = __uint_as_float((uint32_t)(e >> 32));
    a0 += v * __uint_as_float(q << 16);
    a1 += v * __uint_as_float(q & 0xffff0000u);
  }
  float2 o = make_float2(fmaxf(a0, 0.f), fmaxf(a1, 0.f));
  *reinterpret_cast<float2*>(out + (size_t)rid * DOUT + 2 * lane) = o;
}

extern "C" void kernel_launch(void* const* d_in, const int* in_sizes, int n_in,
                              void* d_out, int out_size, void* d_ws, size_t ws_size,
                              hipStream_t stream) {
  const float* x    = (const float*)d_in[0];
  const float* w    = (const float*)d_in[1];
  const int*   rows = (const int*)d_in[2];
  const int*   cols = (const int*)d_in[3];
  const float* vals = (const float*)d_in[4];
  float* out = (float*)d_out;

  // ws layout (u32 units); total = 10,567,940 u32 = 42.3MB (< proven 51.2MB)
  uint32_t* base = (uint32_t*)d_ws;
  uint32_t* preu       = base;                              // 6,400,000
  unsigned short* b16t = (unsigned short*)(base + 6400000); // 65,536 u32
  uint32_t* maskbuf    = base + 6400000 + 65536;            // 800,000
  int* gcnt      = (int*)(base + 6400000 + 65536 + 800000); // 800
  int* bstart    = gcnt + 800;                              // 800
  int* gcursor   = bstart + 800;                            // 800
  int* row_start = gcursor + 800;                           // 100,004
  uint64_t* binned = (uint64_t*)(row_start + 100004);       // 1.6M x 8B
  size_t need = ((size_t)6400000 + 65536 + 800000 + 2400 + 100004 + 3200000) * 4;
  if (ws_size < need) return;  // loud fail

  hipMemsetAsync(gcnt, 0, NB * sizeof(int), stream);

  maskgen<<<(NMASKW + 255) / 256, 256, 0, stream>>>(maskbuf);
  wcvt<<<(NSUP * DIN * DOUT + 255) / 256, 256, 0, stream>>>(w, b16t);

  gemm_mfma2<<<(N_NODES + 127) / 128, 512, 0, stream>>>(x, maskbuf, b16t,
                                                        (unsigned short*)preu);

  count_b<<<NCH, 512, 0, stream>>>(rows, gcnt);
  scan782<<<1, 1024, 0, stream>>>(gcnt, bstart, gcursor);
  bin_scatter<<<NCH, 512, 0, stream>>>(rows, cols, vals, gcursor, binned);
  sort_bucket<<<NB, 512, 0, stream>>>(bstart, binned, row_start);

  spmm_pull<<<(NROWS + 3) / 4, 256, 0, stream>>>(row_start, binned, preu, out);
}

// Round 8
// 208.300 us; speedup vs baseline: 7.0520x; 1.0410x over previous
//
#include <hip/hip_runtime.h>
#include <stdint.h>

#define N_NODES 50000
#define DIN     512
#define DOUT    128
#define NSUP    2
#define EDGES   800000
#define NEDGE   (NSUP * EDGES)        // 1,600,000
#define NROWS   (NSUP * N_NODES)      // 100,000
#define NB      782                   // ceil(NROWS/128)
#define CH      8192                  // edges per chunk
#define NCH     ((NEDGE + CH - 1) / CH)   // 196
#define EPT     16                    // CH / 512 threads
#define SCAP    4096                  // per-bucket LDS edge capacity (max ~2300)
#define NMASKW  ((N_NODES * DIN) / 32)    // 800,000 mask words

typedef __attribute__((ext_vector_type(8))) short short8;
typedef __attribute__((ext_vector_type(4))) float f32x4;

// ---- JAX threefry2x32, key(42) -> (0,42); partitionable, bits = o0^o1 (verified R1) ----
__device__ __forceinline__ uint32_t rotl32(uint32_t v, uint32_t d) {
  return (v << d) | (v >> (32u - d));
}

__device__ __forceinline__ void threefry2x32(uint32_t x0, uint32_t x1,
                                             uint32_t& o0, uint32_t& o1) {
  const uint32_t ks0 = 0u;
  const uint32_t ks1 = 42u;
  const uint32_t ks2 = 0u ^ 42u ^ 0x1BD11BDAu;
  x0 += ks0; x1 += ks1;
#define TF_R(r) { x0 += x1; x1 = rotl32(x1, (r)); x1 ^= x0; }
  TF_R(13) TF_R(15) TF_R(26) TF_R(6)
  x0 += ks1; x1 += ks2 + 1u;
  TF_R(17) TF_R(29) TF_R(16) TF_R(24)
  x0 += ks2; x1 += ks0 + 2u;
  TF_R(13) TF_R(15) TF_R(26) TF_R(6)
  x0 += ks0; x1 += ks1 + 3u;
  TF_R(17) TF_R(29) TF_R(16) TF_R(24)
  x0 += ks1; x1 += ks2 + 4u;
  TF_R(13) TF_R(15) TF_R(26) TF_R(6)
  x0 += ks2; x1 += ks0 + 5u;
#undef TF_R
  o0 = x0; o1 = x1;
}

__device__ __forceinline__ bool keep_mask(uint32_t idx) {
  uint32_t o0, o1;
  threefry2x32(0u, idx, o0, o1);
  uint32_t bits = o0 ^ o1;
  // u = float((bits>>9)|0x3F800000) - 1 < 0.5  <=>  top bit of bits is 0
  return (bits >> 31) == 0u;
}

__device__ __forceinline__ uint32_t pack_bf16x2(float a, float b) {
  uint32_t ua = __float_as_uint(a), ub = __float_as_uint(b);
  ua += 0x7fffu + ((ua >> 16) & 1u);
  ub += 0x7fffu + ((ub >> 16) & 1u);
  return (ua >> 16) | (ub & 0xffff0000u);
}

__device__ __forceinline__ uint32_t bf16rne(float f) {
  uint32_t u = __float_as_uint(f);
  u += 0x7fffu + ((u >> 16) & 1u);
  return u >> 16;
}

// ---- fused: dropout mask generation + bucket histogram ----
// grid 800 x 512. All blocks: 2 mask words/thread (819,200 >= 800,000).
// Blocks < NCH additionally count their 8192-edge chunk into gcnt.
__global__ __launch_bounds__(512) void count_mask(
    const int* __restrict__ rows, int* __restrict__ gcnt,
    uint32_t* __restrict__ maskbuf) {
  const int t = threadIdx.x;
  const int gtid = blockIdx.x * 512 + t;
  // mask slice
#pragma unroll
  for (int q = 0; q < 2; ++q) {
    int wid = gtid * 2 + q;
    if (wid < NMASKW) {
      uint32_t base = (uint32_t)wid * 32u;
      uint32_t m = 0u;
#pragma unroll 4
      for (int j = 0; j < 32; ++j)
        m |= (keep_mask(base + j) ? 1u : 0u) << j;
      maskbuf[wid] = m;
    }
  }
  // edge-count slice
  if (blockIdx.x >= NCH) return;
  __shared__ int hist[NB];
  for (int b = t; b < NB; b += 512) hist[b] = 0;
  __syncthreads();
  int e0 = blockIdx.x * CH;
#pragma unroll
  for (int i = 0; i < EPT; ++i) {
    int e = e0 + i * 512 + t;
    if (e < NEDGE) {
      int s = (e >= EDGES) ? 1 : 0;
      int grow = s * N_NODES + rows[e];
      atomicAdd(&hist[grow >> 7], 1);
    }
  }
  __syncthreads();
  for (int b = t; b < NB; b += 512)
    if (hist[b]) atomicAdd(&gcnt[b], hist[b]);
}

// ---- W [2][512][128] fp32 -> B16t [256 cols][512 k] bf16 (col = s*128+o) ----
__global__ __launch_bounds__(256) void wcvt(const float* __restrict__ w,
                                            unsigned short* __restrict__ b16t) {
  int i = blockIdx.x * 256 + threadIdx.x;
  if (i >= NSUP * DIN * DOUT) return;
  int s   = i >> 16;
  int rem = i & 65535;
  int k   = rem >> 7;
  int o   = rem & 127;
  b16t[(size_t)(s * DOUT + o) * DIN + k] = (unsigned short)bf16rne(w[i]);
}

// ---- bf16 MFMA GEMM with fused mask-apply: BM=128, BN=256, BK=64 ----
__global__ __launch_bounds__(512) void gemm_mfma2(
    const float* __restrict__ x, const uint32_t* __restrict__ maskbuf,
    const unsigned short* __restrict__ b16t,
    unsigned short* __restrict__ pre16) {
  __shared__ unsigned short As[128 * 64];   // 16KB
  __shared__ unsigned short Bs[256 * 64];   // 32KB
  const int t    = threadIdx.x;
  const int lane = t & 63;
  const int w    = t >> 6;
  const int wr   = w >> 2;
  const int wc   = w & 3;
  const int m0   = blockIdx.x * 128;

  f32x4 acc[4][4];
#pragma unroll
  for (int i = 0; i < 4; ++i)
#pragma unroll
    for (int j = 0; j < 4; ++j) acc[i][j] = (f32x4){0.f, 0.f, 0.f, 0.f};

  for (int kc = 0; kc < DIN; kc += 64) {
    __syncthreads();
    // A stage: 128 rows x 64 k of x fp32 + mask-apply + bf16 pack; 2 slots/thread
#pragma unroll
    for (int i = 0; i < 2; ++i) {
      int slot = i * 512 + t;
      int row  = slot >> 3;
      int k8   = (slot & 7) * 8;
      int grow = m0 + row;
      union { uint32_t u[4]; short8 s; } pk;
      if (grow < N_NODES) {
        uint32_t b8 = (uint32_t)grow * DIN + (uint32_t)(kc + k8);
        const float4* src = reinterpret_cast<const float4*>(x + b8);
        float4 v0 = src[0], v1 = src[1];
        float f[8] = {v0.x, v0.y, v0.z, v0.w, v1.x, v1.y, v1.z, v1.w};
        uint32_t bits = maskbuf[b8 >> 5] >> (b8 & 31u);
#pragma unroll
        for (int q = 0; q < 8; ++q)
          f[q] = ((bits >> q) & 1u) ? f[q] * 2.0f : 0.0f;
#pragma unroll
        for (int q = 0; q < 4; ++q) pk.u[q] = pack_bf16x2(f[2 * q], f[2 * q + 1]);
      } else {
#pragma unroll
        for (int q = 0; q < 4; ++q) pk.u[q] = 0u;
      }
      *reinterpret_cast<short8*>(&As[(row * 64 + k8) ^ ((row & 7) << 3)]) = pk.s;
    }
    // B stage: 256x64 bf16 = 2048 short8 slots, 4 per thread
#pragma unroll
    for (int i = 0; i < 4; ++i) {
      int slot = i * 512 + t;
      int col  = slot >> 3;
      int k8   = (slot & 7) * 8;
      short8 v = *reinterpret_cast<const short8*>(
          b16t + (size_t)col * DIN + kc + k8);
      *reinterpret_cast<short8*>(&Bs[(col * 64 + k8) ^ ((col & 7) << 3)]) = v;
    }
    __syncthreads();

    short8 af[4][2], bf[2][4];
#pragma unroll
    for (int mf = 0; mf < 4; ++mf)
#pragma unroll
      for (int kk = 0; kk < 2; ++kk) {
        int row = wr * 64 + mf * 16 + (lane & 15);
        int idx = (row * 64 + kk * 32 + (lane >> 4) * 8) ^ ((row & 7) << 3);
        af[mf][kk] = *reinterpret_cast<const short8*>(&As[idx]);
      }
#pragma unroll
    for (int kk = 0; kk < 2; ++kk)
#pragma unroll
      for (int nf = 0; nf < 4; ++nf) {
        int col = wc * 64 + nf * 16 + (lane & 15);
        int idx = (col * 64 + kk * 32 + (lane >> 4) * 8) ^ ((col & 7) << 3);
        bf[kk][nf] = *reinterpret_cast<const short8*>(&Bs[idx]);
      }
#pragma unroll
    for (int mf = 0; mf < 4; ++mf)
#pragma unroll
      for (int nf = 0; nf < 4; ++nf)
#pragma unroll
        for (int kk = 0; kk < 2; ++kk)
          acc[mf][nf] = __builtin_amdgcn_mfma_f32_16x16x32_bf16(
              af[mf][kk], bf[kk][nf], acc[mf][nf], 0, 0, 0);
  }

  // epilogue: C/D layout col=lane&15, row=(lane>>4)*4+q (m89-verified)
#pragma unroll
  for (int mf = 0; mf < 4; ++mf) {
    int rbase = m0 + wr * 64 + mf * 16 + ((lane >> 4) * 4);
#pragma unroll
    for (int nf = 0; nf < 4; ++nf) {
      int col = wc * 64 + nf * 16 + (lane & 15);
      int s = col >> 7, o = col & 127;
#pragma unroll
      for (int q = 0; q < 4; ++q) {
        int row = rbase + q;
        if (row < N_NODES)
          pre16[(size_t)(s * N_NODES + row) * DOUT + o] =
              (unsigned short)bf16rne(acc[mf][nf][q]);
      }
    }
  }
}

// ---- exclusive scan of 782 bucket counts ----
__global__ __launch_bounds__(1024) void scan782(const int* __restrict__ gcnt,
                                                int* __restrict__ bstart,
                                                int* __restrict__ gcursor) {
  __shared__ int sm[1024];
  int t = threadIdx.x;
  int c = (t < NB) ? gcnt[t] : 0;
  sm[t] = c;
  __syncthreads();
  for (int d = 1; d < 1024; d <<= 1) {
    int v = sm[t];
    int a = (t >= d) ? sm[t - d] : 0;
    __syncthreads();
    sm[t] = v + a;
    __syncthreads();
  }
  if (t < NB) {
    int ex = sm[t] - c;
    bstart[t] = ex;
    gcursor[t] = ex;
  }
  if (t == NB - 1) bstart[NB] = sm[t];
}

// ---- LDS-binned scatter: edges -> binned[] grouped by bucket, coalesced flush ----
__global__ __launch_bounds__(512) void bin_scatter(
    const int* __restrict__ rows, const int* __restrict__ cols,
    const float* __restrict__ vals, int* __restrict__ gcursor,
    uint64_t* __restrict__ binned) {
  __shared__ uint32_t hist[NB];
  __shared__ uint32_t hexcl[NB];
  __shared__ uint32_t sbase[NB];
  __shared__ uint32_t scanb[512];
  __shared__ uint64_t ordered[CH];      // 64KB
  __shared__ uint16_t bk16[CH];         // 16KB
  int t = threadIdx.x;
  for (int b = t; b < NB; b += 512) hist[b] = 0;
  __syncthreads();
  int e0 = blockIdx.x * CH;
  uint32_t key[EPT], rank[EPT], bkt[EPT], vbits[EPT];
#pragma unroll
  for (int i = 0; i < EPT; ++i) {
    int e = e0 + i * 512 + t;
    if (e < NEDGE) {
      int s = (e >= EDGES) ? 1 : 0;
      uint32_t grow = (uint32_t)(s * N_NODES + rows[e]);
      uint32_t gcol = (uint32_t)(s * N_NODES + cols[e]);
      vbits[i] = __float_as_uint(vals[e]);
      uint32_t b = grow >> 7;
      bkt[i] = b;
      key[i] = ((grow & 127u) << 17) | gcol;
      rank[i] = atomicAdd(&hist[b], 1u);
    } else {
      bkt[i] = 0xFFFFFFFFu;
    }
  }
  __syncthreads();
  int t2 = t * 2;
  uint32_t a0 = (t2 < NB) ? hist[t2] : 0u;
  uint32_t a1 = (t2 + 1 < NB) ? hist[t2 + 1] : 0u;
  scanb[t] = a0 + a1;
  __syncthreads();
  for (int d = 1; d < 512; d <<= 1) {
    uint32_t v = scanb[t];
    uint32_t a = (t >= d) ? scanb[t - d] : 0u;
    __syncthreads();
    scanb[t] = v + a;
    __syncthreads();
  }
  uint32_t base  = t ? scanb[t - 1] : 0u;
  uint32_t total = scanb[511];
  if (t2 < NB)     hexcl[t2]     = base;
  if (t2 + 1 < NB) hexcl[t2 + 1] = base + a0;
  for (int b = t; b < NB; b += 512)
    if (hist[b]) sbase[b] = (uint32_t)atomicAdd(&gcursor[b], (int)hist[b]);
  __syncthreads();
#pragma unroll
  for (int i = 0; i < EPT; ++i) {
    if (bkt[i] != 0xFFFFFFFFu) {
      uint32_t slot = hexcl[bkt[i]] + rank[i];
      ordered[slot] = ((uint64_t)vbits[i] << 32) | key[i];
      bk16[slot] = (uint16_t)bkt[i];
    }
  }
  __syncthreads();
#pragma unroll
  for (int i = 0; i < EPT; ++i) {
    uint32_t slot = (uint32_t)(i * 512 + t);
    if (slot < total) {
      uint32_t b = bk16[slot];
      uint32_t dst = sbase[b] + (slot - hexcl[b]);
      binned[dst] = ordered[slot];
    }
  }
}

// ---- fused: per-bucket counting sort (LDS) + pull SpMM + ReLU ----
// block = one 128-row bucket, 512 threads = 8 waves; wave w pulls rows
// w*16 .. w*16+15 sequentially, edges read from sorted LDS (broadcast).
__global__ __launch_bounds__(512) void spmm_sort_pull(
    const int* __restrict__ bstart, const uint64_t* __restrict__ binned,
    const uint32_t* __restrict__ preu, float* __restrict__ out) {
  __shared__ uint64_t ordered[SCAP];    // 32KB
  __shared__ uint32_t hist[128];
  __shared__ uint32_t excl[128];
  const int t = threadIdx.x;
  const int b = blockIdx.x;
  const int beg = bstart[b], end = bstart[b + 1];
  const int cnt = end - beg;
  if (t < 128) hist[t] = 0;
  __syncthreads();
  uint64_t ed[8];
  uint32_t rk[8], rw[8];
#pragma unroll
  for (int i = 0; i < 8; ++i) {
    int slot = i * 512 + t;
    if (slot < cnt) {
      uint64_t e = binned[beg + slot];
      ed[i] = e;
      uint32_t rowin = ((uint32_t)e >> 17) & 127u;
      rw[i] = rowin;
      rk[i] = atomicAdd(&hist[rowin], 1u);
    } else {
      rw[i] = 0xFFFFFFFFu;
    }
  }
  __syncthreads();
  if (t < 128) excl[t] = hist[t];
  __syncthreads();
  for (int d = 1; d < 128; d <<= 1) {
    uint32_t v = (t < 128) ? excl[t] : 0u;
    uint32_t a = (t >= d && t < 128) ? excl[t - d] : 0u;
    __syncthreads();
    if (t < 128) excl[t] = v + a;
    __syncthreads();
  }
  if (t < 128) excl[t] -= hist[t];      // exclusive
  __syncthreads();
#pragma unroll
  for (int i = 0; i < 8; ++i)
    if (rw[i] != 0xFFFFFFFFu)
      ordered[excl[rw[i]] + rk[i]] = ed[i];
  __syncthreads();

  // pull phase: wave w handles 16 rows
  const int lane = t & 63, wave = t >> 6;
  for (int r8 = 0; r8 < 16; ++r8) {
    int r = wave * 16 + r8;
    int grow = b * 128 + r;
    if (grow >= NROWS) break;
    int jbeg = excl[r];
    int jend = jbeg + (int)hist[r];
    float a0 = 0.f, a1 = 0.f;
    int j = jbeg;
    for (; j + 4 <= jend; j += 4) {
      uint64_t e0 = ordered[j],     e1 = ordered[j + 1];
      uint64_t e2 = ordered[j + 2], e3 = ordered[j + 3];
      uint32_t q0 = preu[(size_t)((uint32_t)e0 & 0x1FFFFu) * 64 + lane];
      uint32_t q1 = preu[(size_t)((uint32_t)e1 & 0x1FFFFu) * 64 + lane];
      uint32_t q2 = preu[(size_t)((uint32_t)e2 & 0x1FFFFu) * 64 + lane];
      uint32_t q3 = preu[(size_t)((uint32_t)e3 & 0x1FFFFu) * 64 + lane];
      float v0 = __uint_as_float((uint32_t)(e0 >> 32));
      float v1 = __uint_as_float((uint32_t)(e1 >> 32));
      float v2 = __uint_as_float((uint32_t)(e2 >> 32));
      float v3 = __uint_as_float((uint32_t)(e3 >> 32));
      a0 += v0 * __uint_as_float(q0 << 16);
      a1 += v0 * __uint_as_float(q0 & 0xffff0000u);
      a0 += v1 * __uint_as_float(q1 << 16);
      a1 += v1 * __uint_as_float(q1 & 0xffff0000u);
      a0 += v2 * __uint_as_float(q2 << 16);
      a1 += v2 * __uint_as_float(q2 & 0xffff0000u);
      a0 += v3 * __uint_as_float(q3 << 16);
      a1 += v3 * __uint_as_float(q3 & 0xffff0000u);
    }
    for (; j < jend; ++j) {
      uint64_t e = ordered[j];
      uint32_t q = preu[(size_t)((uint32_t)e & 0x1FFFFu) * 64 + lane];
      float v = __uint_as_float((uint32_t)(e >> 32));
      a0 += v * __uint_as_float(q << 16);
      a1 += v * __uint_as_float(q & 0xffff0000u);
    }
    float2 o = make_float2(fmaxf(a0, 0.f), fmaxf(a1, 0.f));
    *reinterpret_cast<float2*>(out + (size_t)grow * DOUT + 2 * lane) = o;
  }
}

extern "C" void kernel_launch(void* const* d_in, const int* in_sizes, int n_in,
                              void* d_out, int out_size, void* d_ws, size_t ws_size,
                              hipStream_t stream) {
  const float* x    = (const float*)d_in[0];
  const float* w    = (const float*)d_in[1];
  const int*   rows = (const int*)d_in[2];
  const int*   cols = (const int*)d_in[3];
  const float* vals = (const float*)d_in[4];
  float* out = (float*)d_out;

  // ws layout (u32 units); total = 10,467,936 u32 = 41.9MB (< proven 51.2MB)
  uint32_t* base = (uint32_t*)d_ws;
  uint32_t* preu       = base;                              // 6,400,000
  unsigned short* b16t = (unsigned short*)(base + 6400000); // 65,536 u32
  uint32_t* maskbuf    = base + 6400000 + 65536;            // 800,000
  int* gcnt      = (int*)(base + 6400000 + 65536 + 800000); // 800
  int* bstart    = gcnt + 800;                              // 800
  int* gcursor   = bstart + 800;                            // 800
  uint64_t* binned = (uint64_t*)(gcursor + 800);            // 1.6M x 8B (8B-aligned)
  size_t need = ((size_t)6400000 + 65536 + 800000 + 2400 + 3200000) * 4;
  if (ws_size < need) return;  // loud fail

  hipMemsetAsync(gcnt, 0, NB * sizeof(int), stream);

  count_mask<<<800, 512, 0, stream>>>(rows, gcnt, maskbuf);
  scan782<<<1, 1024, 0, stream>>>(gcnt, bstart, gcursor);
  bin_scatter<<<NCH, 512, 0, stream>>>(rows, cols, vals, gcursor, binned);

  wcvt<<<(NSUP * DIN * DOUT + 255) / 256, 256, 0, stream>>>(w, b16t);
  gemm_mfma2<<<(N_NODES + 127) / 128, 512, 0, stream>>>(x, maskbuf, b16t,
                                                        (unsigned short*)preu);

  spmm_sort_pull<<<NB, 512, 0, stream>>>(bstart, binned, preu, out);
}

// Round 9
// 196.027 us; speedup vs baseline: 7.4935x; 1.0626x over previous
//
#include <hip/hip_runtime.h>
#include <stdint.h>

#define N_NODES 50000
#define DIN     512
#define DOUT    128
#define NSUP    2
#define EDGES   800000
#define NEDGE   (NSUP * EDGES)        // 1,600,000
#define NROWS   (NSUP * N_NODES)      // 100,000
#define NB      782                   // ceil(NROWS/128)
#define CH      8192                  // edges per chunk
#define NCH     ((NEDGE + CH - 1) / CH)   // 196
#define EPT     16                    // CH / 512 threads
#define SCAP    4096                  // per-bucket LDS edge capacity (max ~2300)
#define NMASKW  ((N_NODES * DIN) / 32)    // 800,000 mask words
#define NMB     1563                  // mask blocks: 1563*512 = 800,256 threads
#define NWC     256                   // wcvt blocks: 256*512 = 131,072 elems

typedef __attribute__((ext_vector_type(8))) short short8;
typedef __attribute__((ext_vector_type(4))) float f32x4;

// ---- JAX threefry2x32, key(42) -> (0,42); partitionable, bits = o0^o1 (verified R1) ----
__device__ __forceinline__ uint32_t rotl32(uint32_t v, uint32_t d) {
  return (v << d) | (v >> (32u - d));
}

__device__ __forceinline__ void threefry2x32(uint32_t x0, uint32_t x1,
                                             uint32_t& o0, uint32_t& o1) {
  const uint32_t ks0 = 0u;
  const uint32_t ks1 = 42u;
  const uint32_t ks2 = 0u ^ 42u ^ 0x1BD11BDAu;
  x0 += ks0; x1 += ks1;
#define TF_R(r) { x0 += x1; x1 = rotl32(x1, (r)); x1 ^= x0; }
  TF_R(13) TF_R(15) TF_R(26) TF_R(6)
  x0 += ks1; x1 += ks2 + 1u;
  TF_R(17) TF_R(29) TF_R(16) TF_R(24)
  x0 += ks2; x1 += ks0 + 2u;
  TF_R(13) TF_R(15) TF_R(26) TF_R(6)
  x0 += ks0; x1 += ks1 + 3u;
  TF_R(17) TF_R(29) TF_R(16) TF_R(24)
  x0 += ks1; x1 += ks2 + 4u;
  TF_R(13) TF_R(15) TF_R(26) TF_R(6)
  x0 += ks2; x1 += ks0 + 5u;
#undef TF_R
  o0 = x0; o1 = x1;
}

__device__ __forceinline__ bool keep_mask(uint32_t idx) {
  uint32_t o0, o1;
  threefry2x32(0u, idx, o0, o1);
  // u = float(((o0^o1)>>9)|0x3F800000) - 1 < 0.5  <=>  top bit of (o0^o1) is 0
  return ((o0 ^ o1) >> 31) == 0u;
}

__device__ __forceinline__ uint32_t pack_bf16x2(float a, float b) {
  uint32_t ua = __float_as_uint(a), ub = __float_as_uint(b);
  ua += 0x7fffu + ((ua >> 16) & 1u);
  ub += 0x7fffu + ((ub >> 16) & 1u);
  return (ua >> 16) | (ub & 0xffff0000u);
}

__device__ __forceinline__ uint32_t bf16rne(float f) {
  uint32_t u = __float_as_uint(f);
  u += 0x7fffu + ((u >> 16) & 1u);
  return u >> 16;
}

// ---- heterogeneous fused pre-pass ----
// blocks [0, NCH):            edge bucket histogram (memory-bound)
// blocks [NCH, NCH+NMB):      dropout mask, 1 word/thread, unroll-8 ILP (VALU-bound)
// blocks [NCH+NMB, +NWC):     W fp32 -> B16t [256 cols][512 k] bf16 transpose+cvt
__global__ __launch_bounds__(512) void fused_pre(
    const int* __restrict__ rows, const float* __restrict__ w,
    uint32_t* __restrict__ maskbuf, int* __restrict__ gcnt,
    unsigned short* __restrict__ b16t) {
  const int t  = threadIdx.x;
  const int bb = blockIdx.x;
  if (bb < NCH) {
    // --- edge-count slice ---
    __shared__ int hist[NB];
    for (int b = t; b < NB; b += 512) hist[b] = 0;
    __syncthreads();
    int e0 = bb * CH;
#pragma unroll
    for (int i = 0; i < EPT; ++i) {
      int e = e0 + i * 512 + t;
      if (e < NEDGE) {
        int s = (e >= EDGES) ? 1 : 0;
        int grow = s * N_NODES + rows[e];
        atomicAdd(&hist[grow >> 7], 1);
      }
    }
    __syncthreads();
    for (int b = t; b < NB; b += 512)
      if (hist[b]) atomicAdd(&gcnt[b], hist[b]);
  } else if (bb < NCH + NMB) {
    // --- mask slice: one 32-bit word per thread, 8 independent chains ---
    int wid = (bb - NCH) * 512 + t;
    if (wid < NMASKW) {
      uint32_t base = (uint32_t)wid * 32u;
      uint32_t m = 0u;
#pragma unroll 8
      for (int j = 0; j < 32; ++j)
        m |= (keep_mask(base + j) ? 1u : 0u) << j;
      maskbuf[wid] = m;
    }
  } else {
    // --- wcvt slice ---
    int i = (bb - NCH - NMB) * 512 + t;
    if (i < NSUP * DIN * DOUT) {
      int s   = i >> 16;
      int rem = i & 65535;
      int k   = rem >> 7;
      int o   = rem & 127;
      b16t[(size_t)(s * DOUT + o) * DIN + k] = (unsigned short)bf16rne(w[i]);
    }
  }
}

// ---- bf16 MFMA GEMM with fused mask-apply: BM=128, BN=256, BK=64 ----
__global__ __launch_bounds__(512) void gemm_mfma2(
    const float* __restrict__ x, const uint32_t* __restrict__ maskbuf,
    const unsigned short* __restrict__ b16t,
    unsigned short* __restrict__ pre16) {
  __shared__ unsigned short As[128 * 64];   // 16KB
  __shared__ unsigned short Bs[256 * 64];   // 32KB
  const int t    = threadIdx.x;
  const int lane = t & 63;
  const int w    = t >> 6;
  const int wr   = w >> 2;
  const int wc   = w & 3;
  const int m0   = blockIdx.x * 128;

  f32x4 acc[4][4];
#pragma unroll
  for (int i = 0; i < 4; ++i)
#pragma unroll
    for (int j = 0; j < 4; ++j) acc[i][j] = (f32x4){0.f, 0.f, 0.f, 0.f};

  for (int kc = 0; kc < DIN; kc += 64) {
    __syncthreads();
    // A stage: 128 rows x 64 k of x fp32 + mask-apply + bf16 pack; 2 slots/thread
#pragma unroll
    for (int i = 0; i < 2; ++i) {
      int slot = i * 512 + t;
      int row  = slot >> 3;
      int k8   = (slot & 7) * 8;
      int grow = m0 + row;
      union { uint32_t u[4]; short8 s; } pk;
      if (grow < N_NODES) {
        uint32_t b8 = (uint32_t)grow * DIN + (uint32_t)(kc + k8);
        const float4* src = reinterpret_cast<const float4*>(x + b8);
        float4 v0 = src[0], v1 = src[1];
        float f[8] = {v0.x, v0.y, v0.z, v0.w, v1.x, v1.y, v1.z, v1.w};
        uint32_t bits = maskbuf[b8 >> 5] >> (b8 & 31u);
#pragma unroll
        for (int q = 0; q < 8; ++q)
          f[q] = ((bits >> q) & 1u) ? f[q] * 2.0f : 0.0f;
#pragma unroll
        for (int q = 0; q < 4; ++q) pk.u[q] = pack_bf16x2(f[2 * q], f[2 * q + 1]);
      } else {
#pragma unroll
        for (int q = 0; q < 4; ++q) pk.u[q] = 0u;
      }
      *reinterpret_cast<short8*>(&As[(row * 64 + k8) ^ ((row & 7) << 3)]) = pk.s;
    }
    // B stage: 256x64 bf16 = 2048 short8 slots, 4 per thread
#pragma unroll
    for (int i = 0; i < 4; ++i) {
      int slot = i * 512 + t;
      int col  = slot >> 3;
      int k8   = (slot & 7) * 8;
      short8 v = *reinterpret_cast<const short8*>(
          b16t + (size_t)col * DIN + kc + k8);
      *reinterpret_cast<short8*>(&Bs[(col * 64 + k8) ^ ((col & 7) << 3)]) = v;
    }
    __syncthreads();

    short8 af[4][2], bf[2][4];
#pragma unroll
    for (int mf = 0; mf < 4; ++mf)
#pragma unroll
      for (int kk = 0; kk < 2; ++kk) {
        int row = wr * 64 + mf * 16 + (lane & 15);
        int idx = (row * 64 + kk * 32 + (lane >> 4) * 8) ^ ((row & 7) << 3);
        af[mf][kk] = *reinterpret_cast<const short8*>(&As[idx]);
      }
#pragma unroll
    for (int kk = 0; kk < 2; ++kk)
#pragma unroll
      for (int nf = 0; nf < 4; ++nf) {
        int col = wc * 64 + nf * 16 + (lane & 15);
        int idx = (col * 64 + kk * 32 + (lane >> 4) * 8) ^ ((col & 7) << 3);
        bf[kk][nf] = *reinterpret_cast<const short8*>(&Bs[idx]);
      }
#pragma unroll
    for (int mf = 0; mf < 4; ++mf)
#pragma unroll
      for (int nf = 0; nf < 4; ++nf)
#pragma unroll
        for (int kk = 0; kk < 2; ++kk)
          acc[mf][nf] = __builtin_amdgcn_mfma_f32_16x16x32_bf16(
              af[mf][kk], bf[kk][nf], acc[mf][nf], 0, 0, 0);
  }

  // epilogue: C/D layout col=lane&15, row=(lane>>4)*4+q (m89-verified)
#pragma unroll
  for (int mf = 0; mf < 4; ++mf) {
    int rbase = m0 + wr * 64 + mf * 16 + ((lane >> 4) * 4);
#pragma unroll
    for (int nf = 0; nf < 4; ++nf) {
      int col = wc * 64 + nf * 16 + (lane & 15);
      int s = col >> 7, o = col & 127;
#pragma unroll
      for (int q = 0; q < 4; ++q) {
        int row = rbase + q;
        if (row < N_NODES)
          pre16[(size_t)(s * N_NODES + row) * DOUT + o] =
              (unsigned short)bf16rne(acc[mf][nf][q]);
      }
    }
  }
}

// ---- exclusive scan of 782 bucket counts ----
__global__ __launch_bounds__(1024) void scan782(const int* __restrict__ gcnt,
                                                int* __restrict__ bstart,
                                                int* __restrict__ gcursor) {
  __shared__ int sm[1024];
  int t = threadIdx.x;
  int c = (t < NB) ? gcnt[t] : 0;
  sm[t] = c;
  __syncthreads();
  for (int d = 1; d < 1024; d <<= 1) {
    int v = sm[t];
    int a = (t >= d) ? sm[t - d] : 0;
    __syncthreads();
    sm[t] = v + a;
    __syncthreads();
  }
  if (t < NB) {
    int ex = sm[t] - c;
    bstart[t] = ex;
    gcursor[t] = ex;
  }
  if (t == NB - 1) bstart[NB] = sm[t];
}

// ---- LDS-binned scatter: edges -> binned[] grouped by bucket, coalesced flush ----
__global__ __launch_bounds__(512) void bin_scatter(
    const int* __restrict__ rows, const int* __restrict__ cols,
    const float* __restrict__ vals, int* __restrict__ gcursor,
    uint64_t* __restrict__ binned) {
  __shared__ uint32_t hist[NB];
  __shared__ uint32_t hexcl[NB];
  __shared__ uint32_t sbase[NB];
  __shared__ uint32_t scanb[512];
  __shared__ uint64_t ordered[CH];      // 64KB
  __shared__ uint16_t bk16[CH];         // 16KB
  int t = threadIdx.x;
  for (int b = t; b < NB; b += 512) hist[b] = 0;
  __syncthreads();
  int e0 = blockIdx.x * CH;
  uint32_t key[EPT], rank[EPT], bkt[EPT], vbits[EPT];
#pragma unroll
  for (int i = 0; i < EPT; ++i) {
    int e = e0 + i * 512 + t;
    if (e < NEDGE) {
      int s = (e >= EDGES) ? 1 : 0;
      uint32_t grow = (uint32_t)(s * N_NODES + rows[e]);
      uint32_t gcol = (uint32_t)(s * N_NODES + cols[e]);
      vbits[i] = __float_as_uint(vals[e]);
      uint32_t b = grow >> 7;
      bkt[i] = b;
      key[i] = ((grow & 127u) << 17) | gcol;
      rank[i] = atomicAdd(&hist[b], 1u);
    } else {
      bkt[i] = 0xFFFFFFFFu;
    }
  }
  __syncthreads();
  int t2 = t * 2;
  uint32_t a0 = (t2 < NB) ? hist[t2] : 0u;
  uint32_t a1 = (t2 + 1 < NB) ? hist[t2 + 1] : 0u;
  scanb[t] = a0 + a1;
  __syncthreads();
  for (int d = 1; d < 512; d <<= 1) {
    uint32_t v = scanb[t];
    uint32_t a = (t >= d) ? scanb[t - d] : 0u;
    __syncthreads();
    scanb[t] = v + a;
    __syncthreads();
  }
  uint32_t base  = t ? scanb[t - 1] : 0u;
  uint32_t total = scanb[511];
  if (t2 < NB)     hexcl[t2]     = base;
  if (t2 + 1 < NB) hexcl[t2 + 1] = base + a0;
  for (int b = t; b < NB; b += 512)
    if (hist[b]) sbase[b] = (uint32_t)atomicAdd(&gcursor[b], (int)hist[b]);
  __syncthreads();
#pragma unroll
  for (int i = 0; i < EPT; ++i) {
    if (bkt[i] != 0xFFFFFFFFu) {
      uint32_t slot = hexcl[bkt[i]] + rank[i];
      ordered[slot] = ((uint64_t)vbits[i] << 32) | key[i];
      bk16[slot] = (uint16_t)bkt[i];
    }
  }
  __syncthreads();
#pragma unroll
  for (int i = 0; i < EPT; ++i) {
    uint32_t slot = (uint32_t)(i * 512 + t);
    if (slot < total) {
      uint32_t b = bk16[slot];
      uint32_t dst = sbase[b] + (slot - hexcl[b]);
      binned[dst] = ordered[slot];
    }
  }
}

// ---- fused: per-bucket counting sort (LDS) + pull SpMM + ReLU ----
__global__ __launch_bounds__(512) void spmm_sort_pull(
    const int* __restrict__ bstart, const uint64_t* __restrict__ binned,
    const uint32_t* __restrict__ preu, float* __restrict__ out) {
  __shared__ uint64_t ordered[SCAP];    // 32KB
  __shared__ uint32_t hist[128];
  __shared__ uint32_t excl[128];
  const int t = threadIdx.x;
  const int b = blockIdx.x;
  const int beg = bstart[b], end = bstart[b + 1];
  const int cnt = end - beg;
  if (t < 128) hist[t] = 0;
  __syncthreads();
  uint64_t ed[8];
  uint32_t rk[8], rw[8];
#pragma unroll
  for (int i = 0; i < 8; ++i) {
    int slot = i * 512 + t;
    if (slot < cnt) {
      uint64_t e = binned[beg + slot];
      ed[i] = e;
      uint32_t rowin = ((uint32_t)e >> 17) & 127u;
      rw[i] = rowin;
      rk[i] = atomicAdd(&hist[rowin], 1u);
    } else {
      rw[i] = 0xFFFFFFFFu;
    }
  }
  __syncthreads();
  if (t < 128) excl[t] = hist[t];
  __syncthreads();
  for (int d = 1; d < 128; d <<= 1) {
    uint32_t v = (t < 128) ? excl[t] : 0u;
    uint32_t a = (t >= d && t < 128) ? excl[t - d] : 0u;
    __syncthreads();
    if (t < 128) excl[t] = v + a;
    __syncthreads();
  }
  if (t < 128) excl[t] -= hist[t];      // exclusive
  __syncthreads();
#pragma unroll
  for (int i = 0; i < 8; ++i)
    if (rw[i] != 0xFFFFFFFFu)
      ordered[excl[rw[i]] + rk[i]] = ed[i];
  __syncthreads();

  // pull phase: wave w handles 16 rows
  const int lane = t & 63, wave = t >> 6;
  for (int r8 = 0; r8 < 16; ++r8) {
    int r = wave * 16 + r8;
    int grow = b * 128 + r;
    if (grow >= NROWS) break;
    int jbeg = excl[r];
    int jend = jbeg + (int)hist[r];
    float a0 = 0.f, a1 = 0.f;
    int j = jbeg;
    for (; j + 4 <= jend; j += 4) {
      uint64_t e0 = ordered[j],     e1 = ordered[j + 1];
      uint64_t e2 = ordered[j + 2], e3 = ordered[j + 3];
      uint32_t q0 = preu[(size_t)((uint32_t)e0 & 0x1FFFFu) * 64 + lane];
      uint32_t q1 = preu[(size_t)((uint32_t)e1 & 0x1FFFFu) * 64 + lane];
      uint32_t q2 = preu[(size_t)((uint32_t)e2 & 0x1FFFFu) * 64 + lane];
      uint32_t q3 = preu[(size_t)((uint32_t)e3 & 0x1FFFFu) * 64 + lane];
      float v0 = __uint_as_float((uint32_t)(e0 >> 32));
      float v1 = __uint_as_float((uint32_t)(e1 >> 32));
      float v2 = __uint_as_float((uint32_t)(e2 >> 32));
      float v3 = __uint_as_float((uint32_t)(e3 >> 32));
      a0 += v0 * __uint_as_float(q0 << 16);
      a1 += v0 * __uint_as_float(q0 & 0xffff0000u);
      a0 += v1 * __uint_as_float(q1 << 16);
      a1 += v1 * __uint_as_float(q1 & 0xffff0000u);
      a0 += v2 * __uint_as_float(q2 << 16);
      a1 += v2 * __uint_as_float(q2 & 0xffff0000u);
      a0 += v3 * __uint_as_float(q3 << 16);
      a1 += v3 * __uint_as_float(q3 & 0xffff0000u);
    }
    for (; j < jend; ++j) {
      uint64_t e = ordered[j];
      uint32_t q = preu[(size_t)((uint32_t)e & 0x1FFFFu) * 64 + lane];
      float v = __uint_as_float((uint32_t)(e >> 32));
      a0 += v * __uint_as_float(q << 16);
      a1 += v * __uint_as_float(q & 0xffff0000u);
    }
    float2 o = make_float2(fmaxf(a0, 0.f), fmaxf(a1, 0.f));
    *reinterpret_cast<float2*>(out + (size_t)grow * DOUT + 2 * lane) = o;
  }
}

extern "C" void kernel_launch(void* const* d_in, const int* in_sizes, int n_in,
                              void* d_out, int out_size, void* d_ws, size_t ws_size,
                              hipStream_t stream) {
  const float* x    = (const float*)d_in[0];
  const float* w    = (const float*)d_in[1];
  const int*   rows = (const int*)d_in[2];
  const int*   cols = (const int*)d_in[3];
  const float* vals = (const float*)d_in[4];
  float* out = (float*)d_out;

  // ws layout (u32 units); total = 10,467,936 u32 = 41.9MB (< proven 51.2MB)
  uint32_t* base = (uint32_t*)d_ws;
  uint32_t* preu       = base;                              // 6,400,000
  unsigned short* b16t = (unsigned short*)(base + 6400000); // 65,536 u32
  uint32_t* maskbuf    = base + 6400000 + 65536;            // 800,000
  int* gcnt      = (int*)(base + 6400000 + 65536 + 800000); // 800
  int* bstart    = gcnt + 800;                              // 800
  int* gcursor   = bstart + 800;                            // 800
  uint64_t* binned = (uint64_t*)(gcursor + 800);            // 1.6M x 8B (8B-aligned)
  size_t need = ((size_t)6400000 + 65536 + 800000 + 2400 + 3200000) * 4;
  if (ws_size < need) return;  // loud fail

  hipMemsetAsync(gcnt, 0, NB * sizeof(int), stream);

  fused_pre<<<NCH + NMB + NWC, 512, 0, stream>>>(rows, w, maskbuf, gcnt, b16t);
  scan782<<<1, 1024, 0, stream>>>(gcnt, bstart, gcursor);
  bin_scatter<<<NCH, 512, 0, stream>>>(rows, cols, vals, gcursor, binned);

  gemm_mfma2<<<(N_NODES + 127) / 128, 512, 0, stream>>>(x, maskbuf, b16t,
                                                        (unsigned short*)preu);

  spmm_sort_pull<<<NB, 512, 0, stream>>>(bstart, binned, preu, out);
}

// Round 10
// 191.570 us; speedup vs baseline: 7.6678x; 1.0233x over previous
//
#include <hip/hip_runtime.h>
#include <stdint.h>

#define N_NODES 50000
#define DIN     512
#define DOUT    128
#define NSUP    2
#define EDGES   800000
#define NEDGE   (NSUP * EDGES)        // 1,600,000
#define NROWS   (NSUP * N_NODES)      // 100,000
#define NB      782                   // ceil(NROWS/128)
#define CH      8192                  // edges per chunk
#define NCH     ((NEDGE + CH - 1) / CH)   // 196
#define EPT     16                    // CH / 512 threads
#define SCAP    4096                  // per-bucket LDS edge capacity (max ~2300)
#define NMASKW  ((N_NODES * DIN) / 32)    // 800,000 mask words
#define NMB     1563                  // mask blocks: 1563*512 = 800,256 threads
#define NWC     256                   // wcvt blocks: 256*512 = 131,072 elems

typedef __attribute__((ext_vector_type(8))) short short8;
typedef __attribute__((ext_vector_type(4))) float f32x4;

// ---- JAX threefry2x32, key(42) -> (0,42); partitionable, bits = o0^o1 (verified R1) ----
__device__ __forceinline__ uint32_t rotl32(uint32_t v, uint32_t d) {
  return (v << d) | (v >> (32u - d));
}

__device__ __forceinline__ void threefry2x32(uint32_t x0, uint32_t x1,
                                             uint32_t& o0, uint32_t& o1) {
  const uint32_t ks0 = 0u;
  const uint32_t ks1 = 42u;
  const uint32_t ks2 = 0u ^ 42u ^ 0x1BD11BDAu;
  x0 += ks0; x1 += ks1;
#define TF_R(r) { x0 += x1; x1 = rotl32(x1, (r)); x1 ^= x0; }
  TF_R(13) TF_R(15) TF_R(26) TF_R(6)
  x0 += ks1; x1 += ks2 + 1u;
  TF_R(17) TF_R(29) TF_R(16) TF_R(24)
  x0 += ks2; x1 += ks0 + 2u;
  TF_R(13) TF_R(15) TF_R(26) TF_R(6)
  x0 += ks0; x1 += ks1 + 3u;
  TF_R(17) TF_R(29) TF_R(16) TF_R(24)
  x0 += ks1; x1 += ks2 + 4u;
  TF_R(13) TF_R(15) TF_R(26) TF_R(6)
  x0 += ks2; x1 += ks0 + 5u;
#undef TF_R
  o0 = x0; o1 = x1;
}

__device__ __forceinline__ bool keep_mask(uint32_t idx) {
  uint32_t o0, o1;
  threefry2x32(0u, idx, o0, o1);
  // u = float(((o0^o1)>>9)|0x3F800000) - 1 < 0.5  <=>  top bit of (o0^o1) is 0
  return ((o0 ^ o1) >> 31) == 0u;
}

__device__ __forceinline__ uint32_t pack_bf16x2(float a, float b) {
  uint32_t ua = __float_as_uint(a), ub = __float_as_uint(b);
  ua += 0x7fffu + ((ua >> 16) & 1u);
  ub += 0x7fffu + ((ub >> 16) & 1u);
  return (ua >> 16) | (ub & 0xffff0000u);
}

__device__ __forceinline__ uint32_t bf16rne(float f) {
  uint32_t u = __float_as_uint(f);
  u += 0x7fffu + ((u >> 16) & 1u);
  return u >> 16;
}

// ---- heterogeneous fused pre-pass ----
// blocks [0, NCH):            edge bucket histogram (memory-bound)
// blocks [NCH, NCH+NMB):      dropout mask, 1 word/thread, unroll-8 ILP (VALU-bound)
// blocks [NCH+NMB, +NWC):     W fp32 -> B16t [256 cols][512 k] bf16 transpose+cvt
__global__ __launch_bounds__(512) void fused_pre(
    const int* __restrict__ rows, const float* __restrict__ w,
    uint32_t* __restrict__ maskbuf, int* __restrict__ gcnt,
    unsigned short* __restrict__ b16t) {
  const int t  = threadIdx.x;
  const int bb = blockIdx.x;
  if (bb < NCH) {
    __shared__ int hist[NB];
    for (int b = t; b < NB; b += 512) hist[b] = 0;
    __syncthreads();
    int e0 = bb * CH;
#pragma unroll
    for (int i = 0; i < EPT; ++i) {
      int e = e0 + i * 512 + t;
      if (e < NEDGE) {
        int s = (e >= EDGES) ? 1 : 0;
        int grow = s * N_NODES + rows[e];
        atomicAdd(&hist[grow >> 7], 1);
      }
    }
    __syncthreads();
    for (int b = t; b < NB; b += 512)
      if (hist[b]) atomicAdd(&gcnt[b], hist[b]);
  } else if (bb < NCH + NMB) {
    int wid = (bb - NCH) * 512 + t;
    if (wid < NMASKW) {
      uint32_t base = (uint32_t)wid * 32u;
      uint32_t m = 0u;
#pragma unroll 8
      for (int j = 0; j < 32; ++j)
        m |= (keep_mask(base + j) ? 1u : 0u) << j;
      maskbuf[wid] = m;
    }
  } else {
    int i = (bb - NCH - NMB) * 512 + t;
    if (i < NSUP * DIN * DOUT) {
      int s   = i >> 16;
      int rem = i & 65535;
      int k   = rem >> 7;
      int o   = rem & 127;
      b16t[(size_t)(s * DOUT + o) * DIN + k] = (unsigned short)bf16rne(w[i]);
    }
  }
}

// ---- bf16 MFMA GEMM, software-pipelined (register prefetch -> LDS commit) ----
// BM=64, BN=256, BK=64. 512 threads = 8 waves; wave wc owns rows 0..63 x cols
// wc*32..+31 -> acc[4 mf][2 nf]. XOR swizzle on As/Bs (u16 idx ^= (row&7)<<3).
__global__ __launch_bounds__(512) void gemm_mfma3(
    const float* __restrict__ x, const uint32_t* __restrict__ maskbuf,
    const unsigned short* __restrict__ b16t,
    unsigned short* __restrict__ pre16) {
  __shared__ unsigned short As[64 * 64];    // 8KB
  __shared__ unsigned short Bs[256 * 64];   // 32KB
  const int t    = threadIdx.x;
  const int lane = t & 63;
  const int wc   = t >> 6;                  // 0..7
  const int m0   = blockIdx.x * 64;

  f32x4 acc[4][2];
#pragma unroll
  for (int i = 0; i < 4; ++i)
#pragma unroll
    for (int j = 0; j < 2; ++j) acc[i][j] = (f32x4){0.f, 0.f, 0.f, 0.f};

  // A staging geometry: 64 rows x 64 k = 8 fp32/thread
  const int arow  = t >> 3;                 // 0..63
  const int ak8   = (t & 7) * 8;
  const int agrow = m0 + arow;
  const bool avalid = agrow < N_NODES;
  const uint32_t abase = (uint32_t)agrow * DIN + (uint32_t)ak8;
  const int aswz  = (arow * 64 + ak8) ^ ((arow & 7) << 3);

  // prefetch registers
  float4 pa0, pa1;
  uint32_t pm = 0u;
  short8 pb[4];

#define LOADCH(KC)                                                         \
  {                                                                        \
    if (avalid) {                                                          \
      const float4* s_ = reinterpret_cast<const float4*>(x + abase + (KC)); \
      pa0 = s_[0];                                                         \
      pa1 = s_[1];                                                         \
      uint32_t b8_ = abase + (uint32_t)(KC);                               \
      pm = maskbuf[b8_ >> 5] >> (b8_ & 31u);                               \
    }                                                                      \
    _Pragma("unroll")                                                      \
    for (int i_ = 0; i_ < 4; ++i_) {                                       \
      int slot_ = i_ * 512 + t;                                            \
      int col_  = slot_ >> 3;                                              \
      int k8_   = (slot_ & 7) * 8;                                         \
      pb[i_] = *reinterpret_cast<const short8*>(                           \
          b16t + (size_t)col_ * DIN + (KC) + k8_);                         \
    }                                                                      \
  }

  LOADCH(0);

  for (int kc8 = 0; kc8 < 8; ++kc8) {
    const int kc = kc8 * 64;
    __syncthreads();   // LDS free (consumed by previous iteration's frag reads)
    // commit prefetched chunk to LDS (mask-apply + bf16 pack on A)
    {
      union { uint32_t u[4]; short8 s; } pk;
      if (avalid) {
        float f[8] = {pa0.x, pa0.y, pa0.z, pa0.w, pa1.x, pa1.y, pa1.z, pa1.w};
#pragma unroll
        for (int q = 0; q < 8; ++q)
          f[q] = ((pm >> q) & 1u) ? f[q] * 2.0f : 0.0f;
#pragma unroll
        for (int q = 0; q < 4; ++q) pk.u[q] = pack_bf16x2(f[2 * q], f[2 * q + 1]);
      } else {
#pragma unroll
        for (int q = 0; q < 4; ++q) pk.u[q] = 0u;
      }
      *reinterpret_cast<short8*>(&As[aswz]) = pk.s;
    }
#pragma unroll
    for (int i = 0; i < 4; ++i) {
      int slot = i * 512 + t;
      int col  = slot >> 3;
      int k8   = (slot & 7) * 8;
      *reinterpret_cast<short8*>(&Bs[(col * 64 + k8) ^ ((col & 7) << 3)]) = pb[i];
    }
    // issue next chunk's global loads NOW -> latency hides under MFMA phase
    if (kc8 < 7) LOADCH(kc + 64);
    __syncthreads();   // LDS ready

    short8 af[4][2], bf[2][2];
#pragma unroll
    for (int mf = 0; mf < 4; ++mf)
#pragma unroll
      for (int kk = 0; kk < 2; ++kk) {
        int row = mf * 16 + (lane & 15);
        int idx = (row * 64 + kk * 32 + (lane >> 4) * 8) ^ ((row & 7) << 3);
        af[mf][kk] = *reinterpret_cast<const short8*>(&As[idx]);
      }
#pragma unroll
    for (int kk = 0; kk < 2; ++kk)
#pragma unroll
      for (int nf = 0; nf < 2; ++nf) {
        int col = wc * 32 + nf * 16 + (lane & 15);
        int idx = (col * 64 + kk * 32 + (lane >> 4) * 8) ^ ((col & 7) << 3);
        bf[kk][nf] = *reinterpret_cast<const short8*>(&Bs[idx]);
      }
#pragma unroll
    for (int mf = 0; mf < 4; ++mf)
#pragma unroll
      for (int nf = 0; nf < 2; ++nf)
#pragma unroll
        for (int kk = 0; kk < 2; ++kk)
          acc[mf][nf] = __builtin_amdgcn_mfma_f32_16x16x32_bf16(
              af[mf][kk], bf[kk][nf], acc[mf][nf], 0, 0, 0);
  }
#undef LOADCH

  // epilogue: C/D layout col=lane&15, row=(lane>>4)*4+q (m89-verified)
#pragma unroll
  for (int mf = 0; mf < 4; ++mf) {
    int rbase = m0 + mf * 16 + ((lane >> 4) * 4);
#pragma unroll
    for (int nf = 0; nf < 2; ++nf) {
      int col = wc * 32 + nf * 16 + (lane & 15);
      int s = col >> 7, o = col & 127;
#pragma unroll
      for (int q = 0; q < 4; ++q) {
        int row = rbase + q;
        if (row < N_NODES)
          pre16[(size_t)(s * N_NODES + row) * DOUT + o] =
              (unsigned short)bf16rne(acc[mf][nf][q]);
      }
    }
  }
}

// ---- exclusive scan of 782 bucket counts ----
__global__ __launch_bounds__(1024) void scan782(const int* __restrict__ gcnt,
                                                int* __restrict__ bstart,
                                                int* __restrict__ gcursor) {
  __shared__ int sm[1024];
  int t = threadIdx.x;
  int c = (t < NB) ? gcnt[t] : 0;
  sm[t] = c;
  __syncthreads();
  for (int d = 1; d < 1024; d <<= 1) {
    int v = sm[t];
    int a = (t >= d) ? sm[t - d] : 0;
    __syncthreads();
    sm[t] = v + a;
    __syncthreads();
  }
  if (t < NB) {
    int ex = sm[t] - c;
    bstart[t] = ex;
    gcursor[t] = ex;
  }
  if (t == NB - 1) bstart[NB] = sm[t];
}

// ---- LDS-binned scatter: edges -> binned[] grouped by bucket, coalesced flush ----
__global__ __launch_bounds__(512) void bin_scatter(
    const int* __restrict__ rows, const int* __restrict__ cols,
    const float* __restrict__ vals, int* __restrict__ gcursor,
    uint64_t* __restrict__ binned) {
  __shared__ uint32_t hist[NB];
  __shared__ uint32_t hexcl[NB];
  __shared__ uint32_t sbase[NB];
  __shared__ uint32_t scanb[512];
  __shared__ uint64_t ordered[CH];      // 64KB
  __shared__ uint16_t bk16[CH];         // 16KB
  int t = threadIdx.x;
  for (int b = t; b < NB; b += 512) hist[b] = 0;
  __syncthreads();
  int e0 = blockIdx.x * CH;
  uint32_t key[EPT], rank[EPT], bkt[EPT], vbits[EPT];
#pragma unroll
  for (int i = 0; i < EPT; ++i) {
    int e = e0 + i * 512 + t;
    if (e < NEDGE) {
      int s = (e >= EDGES) ? 1 : 0;
      uint32_t grow = (uint32_t)(s * N_NODES + rows[e]);
      uint32_t gcol = (uint32_t)(s * N_NODES + cols[e]);
      vbits[i] = __float_as_uint(vals[e]);
      uint32_t b = grow >> 7;
      bkt[i] = b;
      key[i] = ((grow & 127u) << 17) | gcol;
      rank[i] = atomicAdd(&hist[b], 1u);
    } else {
      bkt[i] = 0xFFFFFFFFu;
    }
  }
  __syncthreads();
  int t2 = t * 2;
  uint32_t a0 = (t2 < NB) ? hist[t2] : 0u;
  uint32_t a1 = (t2 + 1 < NB) ? hist[t2 + 1] : 0u;
  scanb[t] = a0 + a1;
  __syncthreads();
  for (int d = 1; d < 512; d <<= 1) {
    uint32_t v = scanb[t];
    uint32_t a = (t >= d) ? scanb[t - d] : 0u;
    __syncthreads();
    scanb[t] = v + a;
    __syncthreads();
  }
  uint32_t base  = t ? scanb[t - 1] : 0u;
  uint32_t total = scanb[511];
  if (t2 < NB)     hexcl[t2]     = base;
  if (t2 + 1 < NB) hexcl[t2 + 1] = base + a0;
  for (int b = t; b < NB; b += 512)
    if (hist[b]) sbase[b] = (uint32_t)atomicAdd(&gcursor[b], (int)hist[b]);
  __syncthreads();
#pragma unroll
  for (int i = 0; i < EPT; ++i) {
    if (bkt[i] != 0xFFFFFFFFu) {
      uint32_t slot = hexcl[bkt[i]] + rank[i];
      ordered[slot] = ((uint64_t)vbits[i] << 32) | key[i];
      bk16[slot] = (uint16_t)bkt[i];
    }
  }
  __syncthreads();
#pragma unroll
  for (int i = 0; i < EPT; ++i) {
    uint32_t slot = (uint32_t)(i * 512 + t);
    if (slot < total) {
      uint32_t b = bk16[slot];
      uint32_t dst = sbase[b] + (slot - hexcl[b]);
      binned[dst] = ordered[slot];
    }
  }
}

// ---- fused: per-bucket counting sort (LDS) + pull SpMM + ReLU ----
__global__ __launch_bounds__(512) void spmm_sort_pull(
    const int* __restrict__ bstart, const uint64_t* __restrict__ binned,
    const uint32_t* __restrict__ preu, float* __restrict__ out) {
  __shared__ uint64_t ordered[SCAP];    // 32KB
  __shared__ uint32_t hist[128];
  __shared__ uint32_t excl[128];
  const int t = threadIdx.x;
  const int b = blockIdx.x;
  const int beg = bstart[b], end = bstart[b + 1];
  const int cnt = end - beg;
  if (t < 128) hist[t] = 0;
  __syncthreads();
  uint64_t ed[8];
  uint32_t rk[8], rw[8];
#pragma unroll
  for (int i = 0; i < 8; ++i) {
    int slot = i * 512 + t;
    if (slot < cnt) {
      uint64_t e = binned[beg + slot];
      ed[i] = e;
      uint32_t rowin = ((uint32_t)e >> 17) & 127u;
      rw[i] = rowin;
      rk[i] = atomicAdd(&hist[rowin], 1u);
    } else {
      rw[i] = 0xFFFFFFFFu;
    }
  }
  __syncthreads();
  if (t < 128) excl[t] = hist[t];
  __syncthreads();
  for (int d = 1; d < 128; d <<= 1) {
    uint32_t v = (t < 128) ? excl[t] : 0u;
    uint32_t a = (t >= d && t < 128) ? excl[t - d] : 0u;
    __syncthreads();
    if (t < 128) excl[t] = v + a;
    __syncthreads();
  }
  if (t < 128) excl[t] -= hist[t];      // exclusive
  __syncthreads();
#pragma unroll
  for (int i = 0; i < 8; ++i)
    if (rw[i] != 0xFFFFFFFFu)
      ordered[excl[rw[i]] + rk[i]] = ed[i];
  __syncthreads();

  // pull phase: wave w handles 16 rows
  const int lane = t & 63, wave = t >> 6;
  for (int r8 = 0; r8 < 16; ++r8) {
    int r = wave * 16 + r8;
    int grow = b * 128 + r;
    if (grow >= NROWS) break;
    int jbeg = excl[r];
    int jend = jbeg + (int)hist[r];
    float a0 = 0.f, a1 = 0.f;
    int j = jbeg;
    for (; j + 4 <= jend; j += 4) {
      uint64_t e0 = ordered[j],     e1 = ordered[j + 1];
      uint64_t e2 = ordered[j + 2], e3 = ordered[j + 3];
      uint32_t q0 = preu[(size_t)((uint32_t)e0 & 0x1FFFFu) * 64 + lane];
      uint32_t q1 = preu[(size_t)((uint32_t)e1 & 0x1FFFFu) * 64 + lane];
      uint32_t q2 = preu[(size_t)((uint32_t)e2 & 0x1FFFFu) * 64 + lane];
      uint32_t q3 = preu[(size_t)((uint32_t)e3 & 0x1FFFFu) * 64 + lane];
      float v0 = __uint_as_float((uint32_t)(e0 >> 32));
      float v1 = __uint_as_float((uint32_t)(e1 >> 32));
      float v2 = __uint_as_float((uint32_t)(e2 >> 32));
      float v3 = __uint_as_float((uint32_t)(e3 >> 32));
      a0 += v0 * __uint_as_float(q0 << 16);
      a1 += v0 * __uint_as_float(q0 & 0xffff0000u);
      a0 += v1 * __uint_as_float(q1 << 16);
      a1 += v1 * __uint_as_float(q1 & 0xffff0000u);
      a0 += v2 * __uint_as_float(q2 << 16);
      a1 += v2 * __uint_as_float(q2 & 0xffff0000u);
      a0 += v3 * __uint_as_float(q3 << 16);
      a1 += v3 * __uint_as_float(q3 & 0xffff0000u);
    }
    for (; j < jend; ++j) {
      uint64_t e = ordered[j];
      uint32_t q = preu[(size_t)((uint32_t)e & 0x1FFFFu) * 64 + lane];
      float v = __uint_as_float((uint32_t)(e >> 32));
      a0 += v * __uint_as_float(q << 16);
      a1 += v * __uint_as_float(q & 0xffff0000u);
    }
    float2 o = make_float2(fmaxf(a0, 0.f), fmaxf(a1, 0.f));
    *reinterpret_cast<float2*>(out + (size_t)grow * DOUT + 2 * lane) = o;
  }
}

extern "C" void kernel_launch(void* const* d_in, const int* in_sizes, int n_in,
                              void* d_out, int out_size, void* d_ws, size_t ws_size,
                              hipStream_t stream) {
  const float* x    = (const float*)d_in[0];
  const float* w    = (const float*)d_in[1];
  const int*   rows = (const int*)d_in[2];
  const int*   cols = (const int*)d_in[3];
  const float* vals = (const float*)d_in[4];
  float* out = (float*)d_out;

  // ws layout (u32 units); total = 10,467,936 u32 = 41.9MB (< proven 51.2MB)
  uint32_t* base = (uint32_t*)d_ws;
  uint32_t* preu       = base;                              // 6,400,000
  unsigned short* b16t = (unsigned short*)(base + 6400000); // 65,536 u32
  uint32_t* maskbuf    = base + 6400000 + 65536;            // 800,000
  int* gcnt      = (int*)(base + 6400000 + 65536 + 800000); // 800
  int* bstart    = gcnt + 800;                              // 800
  int* gcursor   = bstart + 800;                            // 800
  uint64_t* binned = (uint64_t*)(gcursor + 800);            // 1.6M x 8B (8B-aligned)
  size_t need = ((size_t)6400000 + 65536 + 800000 + 2400 + 3200000) * 4;
  if (ws_size < need) return;  // loud fail

  hipMemsetAsync(gcnt, 0, NB * sizeof(int), stream);

  fused_pre<<<NCH + NMB + NWC, 512, 0, stream>>>(rows, w, maskbuf, gcnt, b16t);
  scan782<<<1, 1024, 0, stream>>>(gcnt, bstart, gcursor);
  bin_scatter<<<NCH, 512, 0, stream>>>(rows, cols, vals, gcursor, binned);

  gemm_mfma3<<<(N_NODES + 63) / 64, 512, 0, stream>>>(x, maskbuf, b16t,
                                                      (unsigned short*)preu);

  spmm_sort_pull<<<NB, 512, 0, stream>>>(bstart, binned, preu, out);
}